// Round 2
// baseline (9511.140 us; speedup 1.0000x reference)
//
#include <hip/hip_runtime.h>

typedef unsigned short u16;

// ---------------- problem constants ----------------
constexpr int NN = 20000;   // nodes
constexpr int EE = 320000;  // edges
constexpr int FD = 128;     // input features
constexpr int C0 = 256;     // hidden (mlp)
constexpr int C1 = 512;     // H*C for GAT
constexpr int NG = 128;     // graphs
constexpr int NC = 10;      // classes

// ---------------- workspace layout (bytes) ----------------
// agg (f32, 41MB) overlaps h1/h2/XB (bf16): all dead before agg is first used.
constexpr size_t OFF_AGG  = 0;                                   // NN*C1 f32
constexpr size_t OFF_H1   = 0;                                   // NN*C0 bf16
constexpr size_t OFF_H2   = (size_t)NN * C0 * 2;                 // NN*C0 bf16
constexpr size_t OFF_XB   = OFF_H2 + (size_t)NN * C0 * 2;        // NN*FD bf16 (x converted), inside agg
constexpr size_t OFF_XW   = (size_t)NN * C1 * 4;                 // NN*C1 bf16
constexpr size_t OFF_H34  = OFF_XW  + (size_t)NN * C1 * 2;       // NN*C1 bf16 (h3 then h4)
constexpr size_t OFF_EBUF = OFF_H34 + (size_t)NN * C1 * 2;       // EE*2 f32
constexpr size_t OFF_PBUF = OFF_EBUF + (size_t)EE * 2 * 4;       // EE*2 f32
constexpr size_t OFF_LS   = OFF_PBUF + (size_t)EE * 2 * 4;       // NN*2 f32
constexpr size_t OFF_LD   = OFF_LS   + (size_t)NN * 2 * 4;
constexpr size_t OFF_NMAX = OFF_LD   + (size_t)NN * 2 * 4;       // NN*2 u32
constexpr size_t OFF_DEN  = OFF_NMAX + (size_t)NN * 2 * 4;
constexpr size_t OFF_POOL = OFF_DEN  + (size_t)NN * 2 * 4;       // NG*C1 f32
constexpr size_t OFF_CNT  = OFF_POOL + (size_t)NG * C1 * 4;      // NG f32 (pad 256)
constexpr size_t OFF_Z1   = OFF_CNT  + 256;                      // NG*C1 bf16
constexpr size_t OFF_Z2   = OFF_Z1   + (size_t)NG * C1 * 2;
constexpr size_t OFF_ST   = OFF_Z2   + (size_t)NG * C1 * 2;      // S1,T1,S2,T2 (256 f32), S3,T3 (512 f32)
constexpr size_t OFF_W1T  = OFF_ST   + 8192;
constexpr size_t OFF_W2T  = OFF_W1T  + (size_t)FD * C0 * 2;
constexpr size_t OFF_G0T  = OFF_W2T  + (size_t)C0 * C0 * 2;
constexpr size_t OFF_G1T  = OFF_G0T  + (size_t)C0 * C1 * 2;
constexpr size_t OFF_AUX  = OFF_G1T  + (size_t)C1 * C1 * 2;
constexpr size_t OFF_FLAG = OFF_AUX  + 0;      // u32
constexpr size_t OFF_A0S  = OFF_AUX  + 256;    // 512 u16
constexpr size_t OFF_A0D  = OFF_AUX  + 1280;
constexpr size_t OFF_A1S  = OFF_AUX  + 2304;
constexpr size_t OFF_A1D  = OFF_AUX  + 3328;
constexpr size_t OFF_GB0  = OFF_AUX  + 4352;   // 512 f32
constexpr size_t OFF_GB1  = OFF_AUX  + 6400;
constexpr size_t OFF_FB1  = OFF_AUX  + 8448;   // 512 f32
constexpr size_t OFF_FB2  = OFF_AUX  + 10496;  // 10 f32
// end ~= 89.2 MB

// ---------------- helpers ----------------
__device__ inline float bf2f(u16 u) { return __uint_as_float(((unsigned)u) << 16); }
__device__ inline u16 f2bf(float f) {
    unsigned u = __float_as_uint(f);
    unsigned r = u + 0x7fffu + ((u >> 16) & 1u);   // RNE
    return (u16)(r >> 16);
}
// flag-driven load of an external float input (flag=1 -> f32, 0 -> bf16)
__device__ inline float ldf(const void* p, long i, unsigned f) {
    return f ? ((const float*)p)[i] : bf2f(((const u16*)p)[i]);
}
__device__ inline unsigned encf(float f) {  // monotonic float->uint for atomicMax
    unsigned u = __float_as_uint(f);
    return (u & 0x80000000u) ? ~u : (u | 0x80000000u);
}
__device__ inline float decf(unsigned e) {
    return (e & 0x80000000u) ? __uint_as_float(e ^ 0x80000000u) : __uint_as_float(~e);
}
__device__ inline void unpack8(uint4 r, float* v) {
    v[0] = bf2f((u16)(r.x & 0xffff)); v[1] = bf2f((u16)(r.x >> 16));
    v[2] = bf2f((u16)(r.y & 0xffff)); v[3] = bf2f((u16)(r.y >> 16));
    v[4] = bf2f((u16)(r.z & 0xffff)); v[5] = bf2f((u16)(r.z >> 16));
    v[6] = bf2f((u16)(r.w & 0xffff)); v[7] = bf2f((u16)(r.w >> 16));
}

typedef __bf16 bf16x8_t __attribute__((ext_vector_type(8)));
typedef float  f32x4_t  __attribute__((ext_vector_type(4)));

// ---------------- dtype detector ----------------
// If inputs are f32 read as u16 pairs, low-halves have ~1/256 chance of a bf16
// NaN/Inf exponent pattern (0xFF). Genuine bf16 normal data has none.
__global__ void detect_dtype(const u16* __restrict__ x, const u16* __restrict__ w,
                             const u16* __restrict__ fw, unsigned* flag) {
    __shared__ int cnt;
    if (threadIdx.x == 0) cnt = 0;
    __syncthreads();
    int c = 0;
    for (int i = threadIdx.x; i < 4096; i += 256) {
        c += (((x[i]  >> 7) & 0xFF) == 0xFF);
        c += (((w[i]  >> 7) & 0xFF) == 0xFF);
        c += (((fw[i] >> 7) & 0xFF) == 0xFF);
    }
    atomicAdd(&cnt, c);
    __syncthreads();
    if (threadIdx.x == 0) *flag = (cnt >= 2) ? 1u : 0u;  // 1 = f32 inputs
}

// ---------------- x -> internal bf16 copy ----------------
__global__ void cvt_x(const unsigned* __restrict__ flag, const void* __restrict__ xin,
                      u16* __restrict__ XB) {
    int i = blockIdx.x * 256 + threadIdx.x;  // grid covers NN*FD/4
    if (*flag) {
        float4 v = ((const float4*)xin)[i];
        ushort4 r;
        r.x = f2bf(v.x); r.y = f2bf(v.y); r.z = f2bf(v.z); r.w = f2bf(v.w);
        ((ushort4*)XB)[i] = r;
    } else {
        ((ushort4*)XB)[i] = ((const ushort4*)xin)[i];
    }
}

// ---------------- params prep: BN scale/shift + small arrays -> known formats ----------------
__global__ void prep_params(const unsigned* __restrict__ flag,
                            const void* g1, const void* b1, const void* m1, const void* v1, const void* lb1,
                            const void* g2, const void* b2, const void* m2, const void* v2, const void* lb2,
                            const void* g3, const void* b3, const void* m3, const void* v3,
                            const void* a0s, const void* a0d, const void* gb0in,
                            const void* a1s, const void* a1d, const void* gb1in,
                            const void* fb1in, const void* fb2in,
                            float* S1, float* T1, float* S2, float* T2, float* S3, float* T3,
                            u16* A0S, u16* A0D, u16* A1S, u16* A1D,
                            float* GB0, float* GB1, float* FB1, float* FB2) {
    unsigned f = *flag;
    int c = threadIdx.x;  // block 512
    if (c < 256) {
        float s = ldf(g1, c, f) / sqrtf(ldf(v1, c, f) + 1e-5f);
        S1[c] = s; T1[c] = s * (ldf(lb1, c, f) - ldf(m1, c, f)) + ldf(b1, c, f);
        float s2 = ldf(g2, c, f) / sqrtf(ldf(v2, c, f) + 1e-5f);
        S2[c] = s2; T2[c] = s2 * (ldf(lb2, c, f) - ldf(m2, c, f)) + ldf(b2, c, f);
    }
    float s3 = ldf(g3, c, f) / sqrtf(ldf(v3, c, f) + 1e-5f);
    S3[c] = s3; T3[c] = ldf(b3, c, f) - ldf(m3, c, f) * s3;
    A0S[c] = f2bf(ldf(a0s, c, f));
    A0D[c] = f2bf(ldf(a0d, c, f));
    A1S[c] = f2bf(ldf(a1s, c, f));
    A1D[c] = f2bf(ldf(a1d, c, f));
    GB0[c] = ldf(gb0in, c, f);
    GB1[c] = ldf(gb1in, c, f);
    FB1[c] = ldf(fb1in, c, f);
    if (c < NC) FB2[c] = ldf(fb2in, c, f);
}

// ---------------- weight transpose+convert (B[K,N] -> BT[N,K] bf16) ----------------
__global__ void transpose_k(const unsigned* __restrict__ flag, const void* __restrict__ B,
                            u16* __restrict__ BT, int K, int N, int logN) {
    int idx = blockIdx.x * 256 + threadIdx.x;
    if (idx >= K * N) return;
    int k = idx >> logN, n = idx & (N - 1);
    u16 v = (*flag) ? f2bf(((const float*)B)[idx]) : ((const u16*)B)[idx];
    BT[(size_t)n * K + k] = v;
}

// ---------------- MFMA GEMM: C[M,N] = A[M,K] @ B[K,N], BT is B transposed ----------------
// EPI: 0 = store raw bf16, 1 = relu(acc*S[col] + T[col])
template <int EPI>
__global__ __launch_bounds__(256) void gemm_bf16(const u16* __restrict__ A, const u16* __restrict__ BT,
                                                 u16* __restrict__ Cm,
                                                 const float* __restrict__ S, const float* __restrict__ T,
                                                 int M, int N, int K) {
    const int wave = threadIdx.x >> 6;
    const int lane = threadIdx.x & 63;
    const int quad = lane >> 4;
    const int l16  = lane & 15;
    const int row0 = blockIdx.x * 64;
    const int col0 = blockIdx.y * 128 + wave * 32;

    f32x4_t acc[4][2];
#pragma unroll
    for (int r = 0; r < 4; r++)
#pragma unroll
        for (int cb = 0; cb < 2; cb++)
#pragma unroll
            for (int i = 0; i < 4; i++) acc[r][cb][i] = 0.f;

    const u16* ap[4];
#pragma unroll
    for (int r = 0; r < 4; r++) {
        int row = row0 + r * 16 + l16;
        if (row >= M) row = M - 1;  // clamp: loads valid, stores guarded
        ap[r] = A + (size_t)row * K + quad * 8;
    }
    const u16* bp[2];
#pragma unroll
    for (int cb = 0; cb < 2; cb++) {
        int col = col0 + cb * 16 + l16;
        bp[cb] = BT + (size_t)col * K + quad * 8;
    }

    for (int k0 = 0; k0 < K; k0 += 32) {
        bf16x8_t a[4], b[2];
#pragma unroll
        for (int r = 0; r < 4; r++) a[r] = *(const bf16x8_t*)(ap[r] + k0);
#pragma unroll
        for (int cb = 0; cb < 2; cb++) b[cb] = *(const bf16x8_t*)(bp[cb] + k0);
#pragma unroll
        for (int r = 0; r < 4; r++)
#pragma unroll
            for (int cb = 0; cb < 2; cb++)
                acc[r][cb] = __builtin_amdgcn_mfma_f32_16x16x32_bf16(a[r], b[cb], acc[r][cb], 0, 0, 0);
    }

#pragma unroll
    for (int r = 0; r < 4; r++) {
        int row_b = row0 + r * 16 + quad * 4;
#pragma unroll
        for (int cb = 0; cb < 2; cb++) {
            int col = col0 + cb * 16 + l16;
            float sc = (EPI == 1) ? S[col] : 0.f;
            float sh = (EPI == 1) ? T[col] : 0.f;
#pragma unroll
            for (int i = 0; i < 4; i++) {
                int row = row_b + i;
                if (row < M) {
                    float v = acc[r][cb][i];
                    if (EPI == 1) v = fmaxf(v * sc + sh, 0.f);
                    Cm[(size_t)row * N + col] = f2bf(v);
                }
            }
        }
    }
}

// ---------------- GAT: per-node attention logits ----------------
__global__ __launch_bounds__(256) void gat_logits(const u16* __restrict__ xw, const u16* __restrict__ asrc,
                                                  const u16* __restrict__ adst, float* __restrict__ ls,
                                                  float* __restrict__ ld) {
    int n = blockIdx.x * 4 + (threadIdx.x >> 6);
    if (n >= NN) return;
    int lane = threadIdx.x & 63;
    uint4 xv = ((const uint4*)(xw + (size_t)n * C1))[lane];
    uint4 sv = ((const uint4*)asrc)[lane];
    uint4 dv = ((const uint4*)adst)[lane];
    float x[8], a[8], d[8];
    unpack8(xv, x); unpack8(sv, a); unpack8(dv, d);
    float ps = 0.f, pd = 0.f;
#pragma unroll
    for (int j = 0; j < 8; j++) { ps += x[j] * a[j]; pd += x[j] * d[j]; }
#pragma unroll
    for (int m = 16; m >= 1; m >>= 1) { ps += __shfl_xor(ps, m); pd += __shfl_xor(pd, m); }
    if ((lane & 31) == 0) {
        int h = lane >> 5;
        ls[n * 2 + h] = ps;
        ld[n * 2 + h] = pd;
    }
}

// ---------------- init: agg=0, nmax=enc(-1e30), den=0 ----------------
__global__ void init_gat(float* agg, unsigned* nmax, float* den) {
    int i = blockIdx.x * 256 + threadIdx.x;  // grid covers NN*C1/4
    float4 z; z.x = z.y = z.z = z.w = 0.f;
    ((float4*)agg)[i] = z;
    if (i < NN * 2) { nmax[i] = encf(-1e30f); den[i] = 0.f; }
}

// ---------------- edge pass 1: logits + segment max ----------------
__global__ void edge_max_k(const int* __restrict__ src, const int* __restrict__ dst, const int* __restrict__ ew,
                           const float* __restrict__ ls, const float* __restrict__ ld,
                           float* __restrict__ ebuf, unsigned* __restrict__ nmax) {
    int e = blockIdx.x * 256 + threadIdx.x;
    if (e >= EE) return;
    int s = src[e], d = dst[e];
    bool ok = (ew[e] == 1);
#pragma unroll
    for (int h = 0; h < 2; h++) {
        float v = ls[s * 2 + h] + ld[d * 2 + h];
        v = v > 0.f ? v : 0.2f * v;  // leaky relu
        ebuf[e * 2 + h] = v;
        if (ok) atomicMax(&nmax[d * 2 + h], encf(v));
    }
}

// ---------------- edge pass 2: exp + segment sum ----------------
__global__ void edge_exp_k(const int* __restrict__ dst, const int* __restrict__ ew,
                           const float* __restrict__ ebuf, const unsigned* __restrict__ nmax,
                           float* __restrict__ pbuf, float* __restrict__ den) {
    int e = blockIdx.x * 256 + threadIdx.x;
    if (e >= EE) return;
    int d = dst[e];
    bool ok = (ew[e] == 1);
#pragma unroll
    for (int h = 0; h < 2; h++) {
        float p = 0.f;
        if (ok) {
            float m = decf(nmax[d * 2 + h]);
            p = expf(ebuf[e * 2 + h] - m);
            atomicAdd(&den[d * 2 + h], p);
        }
        pbuf[e * 2 + h] = p;
    }
}

// ---------------- edge pass 3: weighted scatter-add (wave per edge) ----------------
__global__ __launch_bounds__(256) void edge_scatter_k(const int* __restrict__ src, const int* __restrict__ dst,
                                                      const int* __restrict__ ew, const float* __restrict__ pbuf,
                                                      const float* __restrict__ den, const u16* __restrict__ xw,
                                                      float* __restrict__ agg) {
    int e = blockIdx.x * 4 + (threadIdx.x >> 6);
    if (e >= EE) return;
    if (ew[e] != 1) return;
    int lane = threadIdx.x & 63;
    int h = lane >> 5;
    int s = src[e], d = dst[e];
    float alpha = pbuf[e * 2 + h] / (den[d * 2 + h] + 1e-16f);
    uint4 xv = ((const uint4*)(xw + (size_t)s * C1))[lane];
    float x[8];
    unpack8(xv, x);
    float* arow = agg + (size_t)d * C1 + lane * 8;
#pragma unroll
    for (int j = 0; j < 8; j++) atomicAdd(arow + j, alpha * x[j]);
}

// ---------------- agg(f32) + bias -> bf16 ----------------
__global__ void agg_to_bf16(const float* __restrict__ agg, const float* __restrict__ bias, u16* __restrict__ outh) {
    int i = blockIdx.x * 256 + threadIdx.x;  // grid covers NN*C1/4 exactly
    float4 v = ((const float4*)agg)[i];
    int cb = (i & 127) << 2;
    v.x += bias[cb]; v.y += bias[cb + 1]; v.z += bias[cb + 2]; v.w += bias[cb + 3];
    ushort4 r;
    r.x = f2bf(v.x); r.y = f2bf(v.y); r.z = f2bf(v.z); r.w = f2bf(v.w);
    ((ushort4*)outh)[i] = r;
}

// ---------------- pooling ----------------
__global__ void init_pool(float* pooled, float* cnt) {
    int i = blockIdx.x * 256 + threadIdx.x;
    if (i < NG * C1) pooled[i] = 0.f;
    if (i < NG) cnt[i] = 0.f;
}
__global__ __launch_bounds__(256) void pool_k(const u16* __restrict__ h4, const int* __restrict__ batch,
                                              float* __restrict__ pooled, float* __restrict__ cnt) {
    int n = blockIdx.x * 4 + (threadIdx.x >> 6);
    if (n >= NN) return;
    int lane = threadIdx.x & 63;
    int g = batch[n];
    uint4 xv = ((const uint4*)(h4 + (size_t)n * C1))[lane];
    float x[8];
    unpack8(xv, x);
    float* dstp = pooled + (size_t)g * C1 + lane * 8;
#pragma unroll
    for (int j = 0; j < 8; j++) atomicAdd(dstp + j, x[j]);
    if (lane == 0) atomicAdd(cnt + g, 1.f);
}

// ---------------- head ----------------
__global__ void head_bn3(const float* __restrict__ pooled, const float* __restrict__ cnt,
                         const float* __restrict__ S3, const float* __restrict__ T3, u16* __restrict__ z1) {
    int idx = blockIdx.x * 256 + threadIdx.x;
    if (idx >= NG * C1) return;
    int g = idx >> 9, c = idx & 511;
    float mean = pooled[idx] / fmaxf(cnt[g], 1.f);
    float v = mean * S3[c] + T3[c];
    z1[idx] = f2bf(fmaxf(v, 0.f));
}
__global__ __launch_bounds__(512) void head_fc1(const unsigned* __restrict__ flag, const u16* __restrict__ z1,
                                                const void* __restrict__ w1, const float* __restrict__ FB1,
                                                u16* __restrict__ z2) {
    __shared__ float zrow[512];
    int g = blockIdx.x, t = threadIdx.x;
    zrow[t] = bf2f(z1[(size_t)g * 512 + t]);
    __syncthreads();
    float acc = 0.f;
    if (*flag) {
        const float* w = (const float*)w1;
        for (int k = 0; k < 512; k++) acc = fmaf(zrow[k], w[(size_t)k * 512 + t], acc);
    } else {
        const u16* w = (const u16*)w1;
        for (int k = 0; k < 512; k++) acc = fmaf(zrow[k], bf2f(w[(size_t)k * 512 + t]), acc);
    }
    acc += FB1[t];
    z2[(size_t)g * 512 + t] = f2bf(fmaxf(acc, 0.f));
}
__global__ __launch_bounds__(64) void head_fc2(const unsigned* __restrict__ flag, const u16* __restrict__ z2,
                                               const void* __restrict__ w2, const float* __restrict__ FB2,
                                               void* __restrict__ out) {
    int g = blockIdx.x, o = blockIdx.y, lane = threadIdx.x;
    unsigned f = *flag;
    float acc = 0.f;
    if (f) {
        const float* w = (const float*)w2;
        for (int k = lane; k < 512; k += 64) acc += bf2f(z2[(size_t)g * 512 + k]) * w[(size_t)k * NC + o];
    } else {
        const u16* w = (const u16*)w2;
        for (int k = lane; k < 512; k += 64) acc += bf2f(z2[(size_t)g * 512 + k]) * bf2f(w[(size_t)k * NC + o]);
    }
#pragma unroll
    for (int m = 32; m >= 1; m >>= 1) acc += __shfl_xor(acc, m);
    if (lane == 0) {
        float v = acc + FB2[o];
        if (f) ((float*)out)[g * NC + o] = v;
        else   ((u16*)out)[g * NC + o] = f2bf(v);
    }
}

// ---------------- launch ----------------
extern "C" void kernel_launch(void* const* d_in, const int* in_sizes, int n_in,
                              void* d_out, int out_size, void* d_ws, size_t ws_size,
                              hipStream_t stream) {
    (void)in_sizes; (void)n_in; (void)out_size; (void)ws_size;

    const void* x      = d_in[0];
    const int* ei      = (const int*)d_in[1];
    const int* src     = ei;
    const int* dst     = ei + EE;
    const int* ew      = (const int*)d_in[2];
    const int* batch   = (const int*)d_in[3];
    const void* mlp_w1 = d_in[4];
    const void* mlp_b1 = d_in[5];
    const void *bn1g = d_in[6], *bn1b = d_in[7], *bn1m = d_in[8], *bn1v = d_in[9];
    const void* mlp_w2 = d_in[10];
    const void* mlp_b2 = d_in[11];
    const void *bn2g = d_in[12], *bn2b = d_in[13], *bn2m = d_in[14], *bn2v = d_in[15];
    const void* g0w    = d_in[16];
    const void* g0as   = d_in[17];
    const void* g0ad   = d_in[18];
    const void* g0bias = d_in[19];
    const void* g1w    = d_in[20];
    const void* g1as   = d_in[21];
    const void* g1ad   = d_in[22];
    const void* g1bias = d_in[23];
    const void *bn3g = d_in[24], *bn3b = d_in[25], *bn3m = d_in[26], *bn3v = d_in[27];
    const void* fin_w1 = d_in[28];
    const void* fin_b1 = d_in[29];
    const void* fin_w2 = d_in[30];
    const void* fin_b2 = d_in[31];

    char* ws = (char*)d_ws;
    float*    agg    = (float*)(ws + OFF_AGG);
    u16*      h1     = (u16*)(ws + OFF_H1);
    u16*      h2     = (u16*)(ws + OFF_H2);
    u16*      XB     = (u16*)(ws + OFF_XB);
    u16*      xw     = (u16*)(ws + OFF_XW);
    u16*      h34    = (u16*)(ws + OFF_H34);
    float*    ebuf   = (float*)(ws + OFF_EBUF);
    float*    pbuf   = (float*)(ws + OFF_PBUF);
    float*    ls     = (float*)(ws + OFF_LS);
    float*    ld     = (float*)(ws + OFF_LD);
    unsigned* nmax   = (unsigned*)(ws + OFF_NMAX);
    float*    den    = (float*)(ws + OFF_DEN);
    float*    pooled = (float*)(ws + OFF_POOL);
    float*    cnt    = (float*)(ws + OFF_CNT);
    u16*      z1     = (u16*)(ws + OFF_Z1);
    u16*      z2     = (u16*)(ws + OFF_Z2);
    float*    S1 = (float*)(ws + OFF_ST);
    float*    T1 = S1 + 256;
    float*    S2 = T1 + 256;
    float*    T2 = S2 + 256;
    float*    S3 = T2 + 256;
    float*    T3 = S3 + 512;
    u16* w1T = (u16*)(ws + OFF_W1T);
    u16* w2T = (u16*)(ws + OFF_W2T);
    u16* g0T = (u16*)(ws + OFF_G0T);
    u16* g1T = (u16*)(ws + OFF_G1T);
    unsigned* flag = (unsigned*)(ws + OFF_FLAG);
    u16* A0S = (u16*)(ws + OFF_A0S);
    u16* A0D = (u16*)(ws + OFF_A0D);
    u16* A1S = (u16*)(ws + OFF_A1S);
    u16* A1D = (u16*)(ws + OFF_A1D);
    float* GB0 = (float*)(ws + OFF_GB0);
    float* GB1 = (float*)(ws + OFF_GB1);
    float* FB1 = (float*)(ws + OFF_FB1);
    float* FB2 = (float*)(ws + OFF_FB2);

    // dtype detection + input normalization
    detect_dtype<<<1, 256, 0, stream>>>((const u16*)x, (const u16*)mlp_w1, (const u16*)fin_w1, flag);
    cvt_x<<<(NN * FD / 4) / 256, 256, 0, stream>>>(flag, x, XB);
    prep_params<<<1, 512, 0, stream>>>(flag,
                                       bn1g, bn1b, bn1m, bn1v, mlp_b1,
                                       bn2g, bn2b, bn2m, bn2v, mlp_b2,
                                       bn3g, bn3b, bn3m, bn3v,
                                       g0as, g0ad, g0bias, g1as, g1ad, g1bias,
                                       fin_b1, fin_b2,
                                       S1, T1, S2, T2, S3, T3,
                                       A0S, A0D, A1S, A1D, GB0, GB1, FB1, FB2);
    transpose_k<<<(FD * C0) / 256, 256, 0, stream>>>(flag, mlp_w1, w1T, FD, C0, 8);
    transpose_k<<<(C0 * C0) / 256, 256, 0, stream>>>(flag, mlp_w2, w2T, C0, C0, 8);
    transpose_k<<<(C0 * C1) / 256, 256, 0, stream>>>(flag, g0w, g0T, C0, C1, 9);
    transpose_k<<<(C1 * C1) / 256, 256, 0, stream>>>(flag, g1w, g1T, C1, C1, 9);

    // MLP
    gemm_bf16<1><<<dim3(313, 2), 256, 0, stream>>>(XB, w1T, h1, S1, T1, NN, C0, FD);
    gemm_bf16<1><<<dim3(313, 2), 256, 0, stream>>>(h1, w2T, h2, S2, T2, NN, C0, C0);

    // GAT layer 0
    gemm_bf16<0><<<dim3(313, 4), 256, 0, stream>>>(h2, g0T, xw, nullptr, nullptr, NN, C1, C0);
    gat_logits<<<NN / 4, 256, 0, stream>>>(xw, A0S, A0D, ls, ld);
    init_gat<<<(NN * C1 / 4) / 256, 256, 0, stream>>>(agg, nmax, den);  // clobbers h1/h2/XB (dead)
    edge_max_k<<<EE / 256, 256, 0, stream>>>(src, dst, ew, ls, ld, ebuf, nmax);
    edge_exp_k<<<EE / 256, 256, 0, stream>>>(dst, ew, ebuf, nmax, pbuf, den);
    edge_scatter_k<<<EE / 4, 256, 0, stream>>>(src, dst, ew, pbuf, den, xw, agg);
    agg_to_bf16<<<(NN * C1 / 4) / 256, 256, 0, stream>>>(agg, GB0, h34);

    // GAT layer 1
    gemm_bf16<0><<<dim3(313, 4), 256, 0, stream>>>(h34, g1T, xw, nullptr, nullptr, NN, C1, C1);
    gat_logits<<<NN / 4, 256, 0, stream>>>(xw, A1S, A1D, ls, ld);
    init_gat<<<(NN * C1 / 4) / 256, 256, 0, stream>>>(agg, nmax, den);
    edge_max_k<<<EE / 256, 256, 0, stream>>>(src, dst, ew, ls, ld, ebuf, nmax);
    edge_exp_k<<<EE / 256, 256, 0, stream>>>(dst, ew, ebuf, nmax, pbuf, den);
    edge_scatter_k<<<EE / 4, 256, 0, stream>>>(src, dst, ew, pbuf, den, xw, agg);
    agg_to_bf16<<<(NN * C1 / 4) / 256, 256, 0, stream>>>(agg, GB1, h34);  // h4

    // pool + head
    init_pool<<<(NG * C1) / 256, 256, 0, stream>>>(pooled, cnt);
    pool_k<<<NN / 4, 256, 0, stream>>>(h34, batch, pooled, cnt);
    head_bn3<<<(NG * C1) / 256, 256, 0, stream>>>(pooled, cnt, S3, T3, z1);
    head_fc1<<<NG, 512, 0, stream>>>(flag, z1, fin_w1, FB1, z2);
    head_fc2<<<dim3(NG, NC), 64, 0, stream>>>(flag, z2, fin_w2, FB2, d_out);
}

// Round 3
// 629.708 us; speedup vs baseline: 15.1040x; 15.1040x over previous
//
#include <hip/hip_runtime.h>

typedef unsigned short u16;

// ---------------- problem constants ----------------
constexpr int NN = 20000;   // nodes
constexpr int EE = 320000;  // edges
constexpr int FD = 128;     // input features
constexpr int C0 = 256;     // hidden (mlp)
constexpr int C1 = 512;     // H*C for GAT
constexpr int NG = 128;     // graphs
constexpr int NC = 10;      // classes

// ---------------- workspace layout (bytes) ----------------
constexpr size_t OFF_XB   = 0;                                   // NN*FD bf16
constexpr size_t OFF_H1   = OFF_XB  + (size_t)NN * FD * 2;       // NN*C0 bf16
constexpr size_t OFF_H2   = OFF_H1  + (size_t)NN * C0 * 2;       // NN*C0 bf16
constexpr size_t OFF_XW   = OFF_H2  + (size_t)NN * C0 * 2;       // NN*C1 bf16
constexpr size_t OFF_H34  = OFF_XW  + (size_t)NN * C1 * 2;       // NN*C1 bf16 (h3 then h4)
constexpr size_t OFF_LS   = OFF_H34 + (size_t)NN * C1 * 2;       // NN*2 f32
constexpr size_t OFF_LD   = OFF_LS  + (size_t)NN * 2 * 4;        // NN*2 f32
constexpr size_t OFF_DEG  = OFF_LD  + (size_t)NN * 2 * 4;        // NN i32
constexpr size_t OFF_OFFS = OFF_DEG + (size_t)NN * 4;            // NN+1 i32 (pad 80016)
constexpr size_t OFF_CUR  = OFF_OFFS + 80016;                    // NN i32
constexpr size_t OFF_CSRC = OFF_CUR + (size_t)NN * 4;            // EE i32
constexpr size_t OFF_GCNT = OFF_CSRC + (size_t)EE * 4;           // NG i32
constexpr size_t OFF_GOFF = OFF_GCNT + 512;                      // NG+1 i32 (pad 768)
constexpr size_t OFF_Z1   = OFF_GOFF + 768;                      // NG*C1 bf16
constexpr size_t OFF_Z2   = OFF_Z1  + (size_t)NG * C1 * 2;
constexpr size_t OFF_ST   = OFF_Z2  + (size_t)NG * C1 * 2;       // S1,T1,S2,T2 (256 f32), S3,T3 (512 f32)
constexpr size_t OFF_W1T  = OFF_ST  + 8192;
constexpr size_t OFF_W2T  = OFF_W1T + (size_t)FD * C0 * 2;
constexpr size_t OFF_G0T  = OFF_W2T + (size_t)C0 * C0 * 2;
constexpr size_t OFF_G1T  = OFF_G0T + (size_t)C0 * C1 * 2;
constexpr size_t OFF_AUX  = OFF_G1T + (size_t)C1 * C1 * 2;
constexpr size_t OFF_FLAG = OFF_AUX  + 0;      // u32
constexpr size_t OFF_A0S  = OFF_AUX  + 256;    // 512 u16
constexpr size_t OFF_A0D  = OFF_AUX  + 1280;
constexpr size_t OFF_A1S  = OFF_AUX  + 2304;
constexpr size_t OFF_A1D  = OFF_AUX  + 3328;
constexpr size_t OFF_GB0  = OFF_AUX  + 4352;   // 512 f32
constexpr size_t OFF_GB1  = OFF_AUX  + 6400;
constexpr size_t OFF_FB1  = OFF_AUX  + 8448;   // 512 f32
constexpr size_t OFF_FB2  = OFF_AUX  + 10496;  // 10 f32
// end ~= 70 MB (fits: R2 validated >= 89 MB)

// ---------------- helpers ----------------
__device__ inline float bf2f(u16 u) { return __uint_as_float(((unsigned)u) << 16); }
__device__ inline u16 f2bf(float f) {
    unsigned u = __float_as_uint(f);
    unsigned r = u + 0x7fffu + ((u >> 16) & 1u);   // RNE
    return (u16)(r >> 16);
}
// flag-driven load of an external float input (flag=1 -> f32, 0 -> bf16)
__device__ inline float ldf(const void* p, long i, unsigned f) {
    return f ? ((const float*)p)[i] : bf2f(((const u16*)p)[i]);
}
__device__ inline void unpack8(uint4 r, float* v) {
    v[0] = bf2f((u16)(r.x & 0xffff)); v[1] = bf2f((u16)(r.x >> 16));
    v[2] = bf2f((u16)(r.y & 0xffff)); v[3] = bf2f((u16)(r.y >> 16));
    v[4] = bf2f((u16)(r.z & 0xffff)); v[5] = bf2f((u16)(r.z >> 16));
    v[6] = bf2f((u16)(r.w & 0xffff)); v[7] = bf2f((u16)(r.w >> 16));
}

typedef __bf16 bf16x8_t __attribute__((ext_vector_type(8)));
typedef float  f32x4_t  __attribute__((ext_vector_type(4)));

// ---------------- dtype detector ----------------
__global__ void detect_dtype(const u16* __restrict__ x, const u16* __restrict__ w,
                             const u16* __restrict__ fw, unsigned* flag) {
    __shared__ int cnt;
    if (threadIdx.x == 0) cnt = 0;
    __syncthreads();
    int c = 0;
    for (int i = threadIdx.x; i < 4096; i += 256) {
        c += (((x[i]  >> 7) & 0xFF) == 0xFF);
        c += (((w[i]  >> 7) & 0xFF) == 0xFF);
        c += (((fw[i] >> 7) & 0xFF) == 0xFF);
    }
    atomicAdd(&cnt, c);
    __syncthreads();
    if (threadIdx.x == 0) *flag = (cnt >= 2) ? 1u : 0u;  // 1 = f32 inputs
}

// ---------------- x -> internal bf16 copy ----------------
__global__ void cvt_x(const unsigned* __restrict__ flag, const void* __restrict__ xin,
                      u16* __restrict__ XB) {
    int i = blockIdx.x * 256 + threadIdx.x;  // grid covers NN*FD/4
    if (*flag) {
        float4 v = ((const float4*)xin)[i];
        ushort4 r;
        r.x = f2bf(v.x); r.y = f2bf(v.y); r.z = f2bf(v.z); r.w = f2bf(v.w);
        ((ushort4*)XB)[i] = r;
    } else {
        ((ushort4*)XB)[i] = ((const ushort4*)xin)[i];
    }
}

// ---------------- params prep ----------------
__global__ void prep_params(const unsigned* __restrict__ flag,
                            const void* g1, const void* b1, const void* m1, const void* v1, const void* lb1,
                            const void* g2, const void* b2, const void* m2, const void* v2, const void* lb2,
                            const void* g3, const void* b3, const void* m3, const void* v3,
                            const void* a0s, const void* a0d, const void* gb0in,
                            const void* a1s, const void* a1d, const void* gb1in,
                            const void* fb1in, const void* fb2in,
                            float* S1, float* T1, float* S2, float* T2, float* S3, float* T3,
                            u16* A0S, u16* A0D, u16* A1S, u16* A1D,
                            float* GB0, float* GB1, float* FB1, float* FB2) {
    unsigned f = *flag;
    int c = threadIdx.x;  // block 512
    if (c < 256) {
        float s = ldf(g1, c, f) / sqrtf(ldf(v1, c, f) + 1e-5f);
        S1[c] = s; T1[c] = s * (ldf(lb1, c, f) - ldf(m1, c, f)) + ldf(b1, c, f);
        float s2 = ldf(g2, c, f) / sqrtf(ldf(v2, c, f) + 1e-5f);
        S2[c] = s2; T2[c] = s2 * (ldf(lb2, c, f) - ldf(m2, c, f)) + ldf(b2, c, f);
    }
    float s3 = ldf(g3, c, f) / sqrtf(ldf(v3, c, f) + 1e-5f);
    S3[c] = s3; T3[c] = ldf(b3, c, f) - ldf(m3, c, f) * s3;
    A0S[c] = f2bf(ldf(a0s, c, f));
    A0D[c] = f2bf(ldf(a0d, c, f));
    A1S[c] = f2bf(ldf(a1s, c, f));
    A1D[c] = f2bf(ldf(a1d, c, f));
    GB0[c] = ldf(gb0in, c, f);
    GB1[c] = ldf(gb1in, c, f);
    FB1[c] = ldf(fb1in, c, f);
    if (c < NC) FB2[c] = ldf(fb2in, c, f);
}

// ---------------- weight transpose+convert (B[K,N] -> BT[N,K] bf16) ----------------
__global__ void transpose_k(const unsigned* __restrict__ flag, const void* __restrict__ B,
                            u16* __restrict__ BT, int K, int N, int logN) {
    int idx = blockIdx.x * 256 + threadIdx.x;
    if (idx >= K * N) return;
    int k = idx >> logN, n = idx & (N - 1);
    u16 v = (*flag) ? f2bf(((const float*)B)[idx]) : ((const u16*)B)[idx];
    BT[(size_t)n * K + k] = v;
}

// ---------------- CSR build ----------------
__global__ void init_csr(int* deg, int* gcnt) {
    int i = blockIdx.x * 256 + threadIdx.x;
    if (i < NN) deg[i] = 0;
    if (i < NG) gcnt[i] = 0;
}
__global__ void deg_hist(const int* __restrict__ dst, const int* __restrict__ ew, int* __restrict__ deg) {
    int e = blockIdx.x * 256 + threadIdx.x;
    if (e >= EE) return;
    if (ew[e] == 1) atomicAdd(&deg[dst[e]], 1);
}
__global__ void node_hist(const int* __restrict__ batch, int* __restrict__ gcnt) {
    int n = blockIdx.x * 256 + threadIdx.x;
    if (n >= NN) return;
    atomicAdd(&gcnt[batch[n]], 1);
}
// single-block exclusive scan of deg[NN] -> off[NN+1], cursor copy
__global__ __launch_bounds__(256) void scan_nodes(const int* __restrict__ deg, int* __restrict__ off,
                                                  int* __restrict__ cursor) {
    __shared__ int tmp[256];
    __shared__ int sbase;
    int tid = threadIdx.x;
    if (tid == 0) sbase = 0;
    __syncthreads();
    for (int chunk = 0; chunk * 256 < NN; chunk++) {
        int i = chunk * 256 + tid;
        int v = (i < NN) ? deg[i] : 0;
        tmp[tid] = v;
        __syncthreads();
#pragma unroll
        for (int s = 1; s < 256; s <<= 1) {
            int a = (tid >= s) ? tmp[tid - s] : 0;
            __syncthreads();
            if (tid >= s) tmp[tid] += a;
            __syncthreads();
        }
        int incl = tmp[tid];
        int total = tmp[255];
        int b = sbase;
        if (i < NN) { off[i] = b + incl - v; cursor[i] = b + incl - v; }
        __syncthreads();
        if (tid == 0) sbase = b + total;
        __syncthreads();
    }
    if (tid == 0) off[NN] = sbase;
}
// single-block exclusive scan of gcnt[NG] -> goff[NG+1]
__global__ __launch_bounds__(128) void scan_graphs(const int* __restrict__ gcnt, int* __restrict__ goff) {
    __shared__ int tmp[128];
    int tid = threadIdx.x;
    int v = gcnt[tid];
    tmp[tid] = v;
    __syncthreads();
#pragma unroll
    for (int s = 1; s < 128; s <<= 1) {
        int a = (tid >= s) ? tmp[tid - s] : 0;
        __syncthreads();
        if (tid >= s) tmp[tid] += a;
        __syncthreads();
    }
    goff[tid] = tmp[tid] - v;
    if (tid == 127) goff[128] = tmp[127];
}
__global__ void csr_fill(const int* __restrict__ src, const int* __restrict__ dst, const int* __restrict__ ew,
                         int* __restrict__ cursor, int* __restrict__ csrc) {
    int e = blockIdx.x * 256 + threadIdx.x;
    if (e >= EE) return;
    if (ew[e] != 1) return;
    int p = atomicAdd(&cursor[dst[e]], 1);
    csrc[p] = src[e];
}

// ---------------- MFMA GEMM: C[M,N] = A[M,K] @ B[K,N], BT is B transposed ----------------
// EPI: 0 = store raw bf16, 1 = relu(acc*S[col] + T[col])
template <int EPI>
__global__ __launch_bounds__(256) void gemm_bf16(const u16* __restrict__ A, const u16* __restrict__ BT,
                                                 u16* __restrict__ Cm,
                                                 const float* __restrict__ S, const float* __restrict__ T,
                                                 int M, int N, int K) {
    const int wave = threadIdx.x >> 6;
    const int lane = threadIdx.x & 63;
    const int quad = lane >> 4;
    const int l16  = lane & 15;
    const int row0 = blockIdx.x * 64;
    const int col0 = blockIdx.y * 128 + wave * 32;

    f32x4_t acc[4][2];
#pragma unroll
    for (int r = 0; r < 4; r++)
#pragma unroll
        for (int cb = 0; cb < 2; cb++)
#pragma unroll
            for (int i = 0; i < 4; i++) acc[r][cb][i] = 0.f;

    const u16* ap[4];
#pragma unroll
    for (int r = 0; r < 4; r++) {
        int row = row0 + r * 16 + l16;
        if (row >= M) row = M - 1;  // clamp: loads valid, stores guarded
        ap[r] = A + (size_t)row * K + quad * 8;
    }
    const u16* bp[2];
#pragma unroll
    for (int cb = 0; cb < 2; cb++) {
        int col = col0 + cb * 16 + l16;
        bp[cb] = BT + (size_t)col * K + quad * 8;
    }

    for (int k0 = 0; k0 < K; k0 += 32) {
        bf16x8_t a[4], b[2];
#pragma unroll
        for (int r = 0; r < 4; r++) a[r] = *(const bf16x8_t*)(ap[r] + k0);
#pragma unroll
        for (int cb = 0; cb < 2; cb++) b[cb] = *(const bf16x8_t*)(bp[cb] + k0);
#pragma unroll
        for (int r = 0; r < 4; r++)
#pragma unroll
            for (int cb = 0; cb < 2; cb++)
                acc[r][cb] = __builtin_amdgcn_mfma_f32_16x16x32_bf16(a[r], b[cb], acc[r][cb], 0, 0, 0);
    }

#pragma unroll
    for (int r = 0; r < 4; r++) {
        int row_b = row0 + r * 16 + quad * 4;
#pragma unroll
        for (int cb = 0; cb < 2; cb++) {
            int col = col0 + cb * 16 + l16;
            float sc = (EPI == 1) ? S[col] : 0.f;
            float sh = (EPI == 1) ? T[col] : 0.f;
#pragma unroll
            for (int i = 0; i < 4; i++) {
                int row = row_b + i;
                if (row < M) {
                    float v = acc[r][cb][i];
                    if (EPI == 1) v = fmaxf(v * sc + sh, 0.f);
                    Cm[(size_t)row * N + col] = f2bf(v);
                }
            }
        }
    }
}

// ---------------- GAT: per-node attention logits ----------------
__global__ __launch_bounds__(256) void gat_logits(const u16* __restrict__ xw, const u16* __restrict__ asrc,
                                                  const u16* __restrict__ adst, float* __restrict__ ls,
                                                  float* __restrict__ ld) {
    int n = blockIdx.x * 4 + (threadIdx.x >> 6);
    if (n >= NN) return;
    int lane = threadIdx.x & 63;
    uint4 xv = ((const uint4*)(xw + (size_t)n * C1))[lane];
    uint4 sv = ((const uint4*)asrc)[lane];
    uint4 dv = ((const uint4*)adst)[lane];
    float x[8], a[8], d[8];
    unpack8(xv, x); unpack8(sv, a); unpack8(dv, d);
    float ps = 0.f, pd = 0.f;
#pragma unroll
    for (int j = 0; j < 8; j++) { ps += x[j] * a[j]; pd += x[j] * d[j]; }
#pragma unroll
    for (int m = 16; m >= 1; m >>= 1) { ps += __shfl_xor(ps, m); pd += __shfl_xor(pd, m); }
    if ((lane & 31) == 0) {
        int h = lane >> 5;
        ls[n * 2 + h] = ps;
        ld[n * 2 + h] = pd;
    }
}

// ---------------- fused GAT aggregation: softmax + gather, one wave per node ----------------
// lanes 0..31 -> head 0, lanes 32..63 -> head 1; lane covers features [lane*8, lane*8+8)
__global__ __launch_bounds__(256) void gat_aggregate(const int* __restrict__ off, const int* __restrict__ csrc,
                                                     const float* __restrict__ ls, const float* __restrict__ ld,
                                                     const u16* __restrict__ xw, const float* __restrict__ bias,
                                                     u16* __restrict__ outh) {
    int n = blockIdx.x * 4 + (threadIdx.x >> 6);
    if (n >= NN) return;
    int lane = threadIdx.x & 63;
    int h = lane >> 5;
    int l32 = lane & 31;
    int beg = off[n], end = off[n + 1];
    float ldh = ld[n * 2 + h];

    // pass 1: per-head max over edges (half-wave strided)
    float m = -1e30f;
    for (int i = beg + l32; i < end; i += 32) {
        int s = csrc[i];
        float v = ls[s * 2 + h] + ldh;
        v = v > 0.f ? v : 0.2f * v;
        m = fmaxf(m, v);
    }
#pragma unroll
    for (int o = 16; o >= 1; o >>= 1) m = fmaxf(m, __shfl_xor(m, o));

    // pass 2: per-head sum of exp
    float den = 0.f;
    for (int i = beg + l32; i < end; i += 32) {
        int s = csrc[i];
        float v = ls[s * 2 + h] + ldh;
        v = v > 0.f ? v : 0.2f * v;
        den += __expf(v - m);
    }
#pragma unroll
    for (int o = 16; o >= 1; o >>= 1) den += __shfl_xor(den, o);
    float inv = 1.f / (den + 1e-16f);

    // pass 3: serial edge loop, all lanes gather features
    float acc[8];
#pragma unroll
    for (int j = 0; j < 8; j++) acc[j] = 0.f;
    for (int i = beg; i < end; i++) {
        int s = csrc[i];
        float v = ls[s * 2 + h] + ldh;
        v = v > 0.f ? v : 0.2f * v;
        float alpha = __expf(v - m) * inv;
        uint4 xv = ((const uint4*)(xw + (size_t)s * C1))[lane];
        float x[8];
        unpack8(xv, x);
#pragma unroll
        for (int j = 0; j < 8; j++) acc[j] = fmaf(alpha, x[j], acc[j]);
    }

    ushort4 r0, r1;
    int cb = lane * 8;
    float o0 = acc[0] + bias[cb + 0], o1 = acc[1] + bias[cb + 1];
    float o2 = acc[2] + bias[cb + 2], o3 = acc[3] + bias[cb + 3];
    float o4 = acc[4] + bias[cb + 4], o5 = acc[5] + bias[cb + 5];
    float o6 = acc[6] + bias[cb + 6], o7 = acc[7] + bias[cb + 7];
    r0.x = f2bf(o0); r0.y = f2bf(o1); r0.z = f2bf(o2); r0.w = f2bf(o3);
    r1.x = f2bf(o4); r1.y = f2bf(o5); r1.z = f2bf(o6); r1.w = f2bf(o7);
    ushort4* dst4 = (ushort4*)(outh + (size_t)n * C1 + cb);
    dst4[0] = r0; dst4[1] = r1;
}

// ---------------- fused pool + BN3 + ReLU (block per graph; batch is sorted) ----------------
__global__ __launch_bounds__(512) void pool_bn(const u16* __restrict__ h4, const int* __restrict__ goff,
                                               const float* __restrict__ S3, const float* __restrict__ T3,
                                               u16* __restrict__ z1) {
    int g = blockIdx.x, t = threadIdx.x;
    int b = goff[g], e = goff[g + 1];
    float s = 0.f;
    for (int n = b; n < e; n++) s += bf2f(h4[(size_t)n * C1 + t]);
    float mean = s / fmaxf((float)(e - b), 1.f);
    float v = mean * S3[t] + T3[t];
    z1[(size_t)g * C1 + t] = f2bf(fmaxf(v, 0.f));
}

// ---------------- head ----------------
__global__ __launch_bounds__(512) void head_fc1(const unsigned* __restrict__ flag, const u16* __restrict__ z1,
                                                const void* __restrict__ w1, const float* __restrict__ FB1,
                                                u16* __restrict__ z2) {
    __shared__ float zrow[512];
    int g = blockIdx.x, t = threadIdx.x;
    zrow[t] = bf2f(z1[(size_t)g * 512 + t]);
    __syncthreads();
    float acc = 0.f;
    if (*flag) {
        const float* w = (const float*)w1;
        for (int k = 0; k < 512; k++) acc = fmaf(zrow[k], w[(size_t)k * 512 + t], acc);
    } else {
        const u16* w = (const u16*)w1;
        for (int k = 0; k < 512; k++) acc = fmaf(zrow[k], bf2f(w[(size_t)k * 512 + t]), acc);
    }
    acc += FB1[t];
    z2[(size_t)g * 512 + t] = f2bf(fmaxf(acc, 0.f));
}
__global__ __launch_bounds__(64) void head_fc2(const unsigned* __restrict__ flag, const u16* __restrict__ z2,
                                               const void* __restrict__ w2, const float* __restrict__ FB2,
                                               void* __restrict__ out) {
    int g = blockIdx.x, o = blockIdx.y, lane = threadIdx.x;
    unsigned f = *flag;
    float acc = 0.f;
    if (f) {
        const float* w = (const float*)w2;
        for (int k = lane; k < 512; k += 64) acc += bf2f(z2[(size_t)g * 512 + k]) * w[(size_t)k * NC + o];
    } else {
        const u16* w = (const u16*)w2;
        for (int k = lane; k < 512; k += 64) acc += bf2f(z2[(size_t)g * 512 + k]) * bf2f(w[(size_t)k * NC + o]);
    }
#pragma unroll
    for (int m = 32; m >= 1; m >>= 1) acc += __shfl_xor(acc, m);
    if (lane == 0) {
        float v = acc + FB2[o];
        if (f) ((float*)out)[g * NC + o] = v;
        else   ((u16*)out)[g * NC + o] = f2bf(v);
    }
}

// ---------------- launch ----------------
extern "C" void kernel_launch(void* const* d_in, const int* in_sizes, int n_in,
                              void* d_out, int out_size, void* d_ws, size_t ws_size,
                              hipStream_t stream) {
    (void)in_sizes; (void)n_in; (void)out_size; (void)ws_size;

    const void* x      = d_in[0];
    const int* ei      = (const int*)d_in[1];
    const int* src     = ei;
    const int* dst     = ei + EE;
    const int* ew      = (const int*)d_in[2];
    const int* batch   = (const int*)d_in[3];
    const void* mlp_w1 = d_in[4];
    const void* mlp_b1 = d_in[5];
    const void *bn1g = d_in[6], *bn1b = d_in[7], *bn1m = d_in[8], *bn1v = d_in[9];
    const void* mlp_w2 = d_in[10];
    const void* mlp_b2 = d_in[11];
    const void *bn2g = d_in[12], *bn2b = d_in[13], *bn2m = d_in[14], *bn2v = d_in[15];
    const void* g0w    = d_in[16];
    const void* g0as   = d_in[17];
    const void* g0ad   = d_in[18];
    const void* g0bias = d_in[19];
    const void* g1w    = d_in[20];
    const void* g1as   = d_in[21];
    const void* g1ad   = d_in[22];
    const void* g1bias = d_in[23];
    const void *bn3g = d_in[24], *bn3b = d_in[25], *bn3m = d_in[26], *bn3v = d_in[27];
    const void* fin_w1 = d_in[28];
    const void* fin_b1 = d_in[29];
    const void* fin_w2 = d_in[30];
    const void* fin_b2 = d_in[31];

    char* ws = (char*)d_ws;
    u16*  XB   = (u16*)(ws + OFF_XB);
    u16*  h1   = (u16*)(ws + OFF_H1);
    u16*  h2   = (u16*)(ws + OFF_H2);
    u16*  xw   = (u16*)(ws + OFF_XW);
    u16*  h34  = (u16*)(ws + OFF_H34);
    float* ls  = (float*)(ws + OFF_LS);
    float* ld  = (float*)(ws + OFF_LD);
    int*  deg  = (int*)(ws + OFF_DEG);
    int*  off  = (int*)(ws + OFF_OFFS);
    int*  cur  = (int*)(ws + OFF_CUR);
    int*  csrc = (int*)(ws + OFF_CSRC);
    int*  gcnt = (int*)(ws + OFF_GCNT);
    int*  goff = (int*)(ws + OFF_GOFF);
    u16*  z1   = (u16*)(ws + OFF_Z1);
    u16*  z2   = (u16*)(ws + OFF_Z2);
    float* S1 = (float*)(ws + OFF_ST);
    float* T1 = S1 + 256;
    float* S2 = T1 + 256;
    float* T2 = S2 + 256;
    float* S3 = T2 + 256;
    float* T3 = S3 + 512;
    u16* w1T = (u16*)(ws + OFF_W1T);
    u16* w2T = (u16*)(ws + OFF_W2T);
    u16* g0T = (u16*)(ws + OFF_G0T);
    u16* g1T = (u16*)(ws + OFF_G1T);
    unsigned* flag = (unsigned*)(ws + OFF_FLAG);
    u16* A0S = (u16*)(ws + OFF_A0S);
    u16* A0D = (u16*)(ws + OFF_A0D);
    u16* A1S = (u16*)(ws + OFF_A1S);
    u16* A1D = (u16*)(ws + OFF_A1D);
    float* GB0 = (float*)(ws + OFF_GB0);
    float* GB1 = (float*)(ws + OFF_GB1);
    float* FB1 = (float*)(ws + OFF_FB1);
    float* FB2 = (float*)(ws + OFF_FB2);

    // dtype detection + input normalization
    detect_dtype<<<1, 256, 0, stream>>>((const u16*)x, (const u16*)mlp_w1, (const u16*)fin_w1, flag);
    cvt_x<<<(NN * FD / 4) / 256, 256, 0, stream>>>(flag, x, XB);
    prep_params<<<1, 512, 0, stream>>>(flag,
                                       bn1g, bn1b, bn1m, bn1v, mlp_b1,
                                       bn2g, bn2b, bn2m, bn2v, mlp_b2,
                                       bn3g, bn3b, bn3m, bn3v,
                                       g0as, g0ad, g0bias, g1as, g1ad, g1bias,
                                       fin_b1, fin_b2,
                                       S1, T1, S2, T2, S3, T3,
                                       A0S, A0D, A1S, A1D, GB0, GB1, FB1, FB2);
    transpose_k<<<(FD * C0) / 256, 256, 0, stream>>>(flag, mlp_w1, w1T, FD, C0, 8);
    transpose_k<<<(C0 * C0) / 256, 256, 0, stream>>>(flag, mlp_w2, w2T, C0, C0, 8);
    transpose_k<<<(C0 * C1) / 256, 256, 0, stream>>>(flag, g0w, g0T, C0, C1, 9);
    transpose_k<<<(C1 * C1) / 256, 256, 0, stream>>>(flag, g1w, g1T, C1, C1, 9);

    // CSR build (graph fixed across both layers) + graph offsets
    init_csr<<<(NN + 255) / 256, 256, 0, stream>>>(deg, gcnt);
    deg_hist<<<EE / 256, 256, 0, stream>>>(dst, ew, deg);
    node_hist<<<(NN + 255) / 256, 256, 0, stream>>>(batch, gcnt);
    scan_nodes<<<1, 256, 0, stream>>>(deg, off, cur);
    scan_graphs<<<1, 128, 0, stream>>>(gcnt, goff);
    csr_fill<<<EE / 256, 256, 0, stream>>>(src, dst, ew, cur, csrc);

    // MLP
    gemm_bf16<1><<<dim3(313, 2), 256, 0, stream>>>(XB, w1T, h1, S1, T1, NN, C0, FD);
    gemm_bf16<1><<<dim3(313, 2), 256, 0, stream>>>(h1, w2T, h2, S2, T2, NN, C0, C0);

    // GAT layer 0
    gemm_bf16<0><<<dim3(313, 4), 256, 0, stream>>>(h2, g0T, xw, nullptr, nullptr, NN, C1, C0);
    gat_logits<<<NN / 4, 256, 0, stream>>>(xw, A0S, A0D, ls, ld);
    gat_aggregate<<<NN / 4, 256, 0, stream>>>(off, csrc, ls, ld, xw, GB0, h34);

    // GAT layer 1
    gemm_bf16<0><<<dim3(313, 4), 256, 0, stream>>>(h34, g1T, xw, nullptr, nullptr, NN, C1, C1);
    gat_logits<<<NN / 4, 256, 0, stream>>>(xw, A1S, A1D, ls, ld);
    gat_aggregate<<<NN / 4, 256, 0, stream>>>(off, csrc, ls, ld, xw, GB1, h34);  // h4

    // pool + head
    pool_bn<<<NG, 512, 0, stream>>>(h34, goff, S3, T3, z1);
    head_fc1<<<NG, 512, 0, stream>>>(flag, z1, fin_w1, FB1, z2);
    head_fc2<<<dim3(NG, NC), 64, 0, stream>>>(flag, z2, fin_w2, FB2, d_out);
}

// Round 4
// 543.968 us; speedup vs baseline: 17.4847x; 1.1576x over previous
//
#include <hip/hip_runtime.h>

typedef unsigned short u16;

// ---------------- problem constants ----------------
constexpr int NN = 20000;   // nodes
constexpr int EE = 320000;  // edges
constexpr int FD = 128;     // input features
constexpr int C0 = 256;     // hidden (mlp)
constexpr int C1 = 512;     // H*C for GAT
constexpr int NG = 128;     // graphs
constexpr int NC = 10;      // classes
constexpr int NBLK = (NN + 255) / 256;  // 79

// ---------------- workspace layout (bytes) ----------------
constexpr size_t OFF_XB   = 0;                                   // NN*FD bf16
constexpr size_t OFF_H1   = OFF_XB  + (size_t)NN * FD * 2;       // NN*C0 bf16
constexpr size_t OFF_H2   = OFF_H1  + (size_t)NN * C0 * 2;       // NN*C0 bf16
constexpr size_t OFF_XW   = OFF_H2  + (size_t)NN * C0 * 2;       // NN*C1 bf16
constexpr size_t OFF_H34  = OFF_XW  + (size_t)NN * C1 * 2;       // NN*C1 bf16 (h3 then h4)
constexpr size_t OFF_LS   = OFF_H34 + (size_t)NN * C1 * 2;       // NN*2 f32
constexpr size_t OFF_LD   = OFF_LS  + (size_t)NN * 2 * 4;        // NN*2 f32
constexpr size_t OFF_DEG  = OFF_LD  + (size_t)NN * 2 * 4;        // NN i32
constexpr size_t OFF_OFFS = OFF_DEG + (size_t)NN * 4;            // NN+1 i32 (pad 80016)
constexpr size_t OFF_CUR  = OFF_OFFS + 80016;                    // NN i32
constexpr size_t OFF_CSRC = OFF_CUR + (size_t)NN * 4;            // EE i32
constexpr size_t OFF_GCNT = OFF_CSRC + (size_t)EE * 4;           // NG i32
constexpr size_t OFF_GOFF = OFF_GCNT + 512;                      // NG+1 i32 (pad 768)
constexpr size_t OFF_PART = OFF_GOFF + 768;                      // NBLK i32 (pad 512)
constexpr size_t OFF_PTOT = OFF_PART + 512;                      // 1 i32 (pad 256)
constexpr size_t OFF_Z1   = OFF_PTOT + 256;                      // NG*C1 bf16
constexpr size_t OFF_Z2   = OFF_Z1  + (size_t)NG * C1 * 2;
constexpr size_t OFF_ST   = OFF_Z2  + (size_t)NG * C1 * 2;       // S1,T1,S2,T2 (256 f32), S3,T3 (512 f32)
constexpr size_t OFF_W1T  = OFF_ST  + 8192;
constexpr size_t OFF_W2T  = OFF_W1T + (size_t)FD * C0 * 2;
constexpr size_t OFF_G0T  = OFF_W2T + (size_t)C0 * C0 * 2;
constexpr size_t OFF_G1T  = OFF_G0T + (size_t)C0 * C1 * 2;
constexpr size_t OFF_AUX  = OFF_G1T + (size_t)C1 * C1 * 2;
constexpr size_t OFF_FLAG = OFF_AUX  + 0;      // u32
constexpr size_t OFF_A0S  = OFF_AUX  + 256;    // 512 u16
constexpr size_t OFF_A0D  = OFF_AUX  + 1280;
constexpr size_t OFF_A1S  = OFF_AUX  + 2304;
constexpr size_t OFF_A1D  = OFF_AUX  + 3328;
constexpr size_t OFF_GB0  = OFF_AUX  + 4352;   // 512 f32
constexpr size_t OFF_GB1  = OFF_AUX  + 6400;
constexpr size_t OFF_FB1  = OFF_AUX  + 8448;   // 512 f32
constexpr size_t OFF_FB2  = OFF_AUX  + 10496;  // 10 f32
// end ~= 70 MB

// ---------------- helpers ----------------
__device__ inline float bf2f(u16 u) { return __uint_as_float(((unsigned)u) << 16); }
__device__ inline u16 f2bf(float f) {
    unsigned u = __float_as_uint(f);
    unsigned r = u + 0x7fffu + ((u >> 16) & 1u);   // RNE
    return (u16)(r >> 16);
}
// flag-driven load of an external float input (flag=1 -> f32, 0 -> bf16)
__device__ inline float ldf(const void* p, long i, unsigned f) {
    return f ? ((const float*)p)[i] : bf2f(((const u16*)p)[i]);
}
__device__ inline void unpack8(uint4 r, float* v) {
    v[0] = bf2f((u16)(r.x & 0xffff)); v[1] = bf2f((u16)(r.x >> 16));
    v[2] = bf2f((u16)(r.y & 0xffff)); v[3] = bf2f((u16)(r.y >> 16));
    v[4] = bf2f((u16)(r.z & 0xffff)); v[5] = bf2f((u16)(r.z >> 16));
    v[6] = bf2f((u16)(r.w & 0xffff)); v[7] = bf2f((u16)(r.w >> 16));
}

typedef __bf16 bf16x8_t __attribute__((ext_vector_type(8)));
typedef float  f32x4_t  __attribute__((ext_vector_type(4)));

// ---------------- dtype detector ----------------
__global__ void detect_dtype(const u16* __restrict__ x, const u16* __restrict__ w,
                             const u16* __restrict__ fw, unsigned* flag) {
    __shared__ int cnt;
    if (threadIdx.x == 0) cnt = 0;
    __syncthreads();
    int c = 0;
    for (int i = threadIdx.x; i < 4096; i += 256) {
        c += (((x[i]  >> 7) & 0xFF) == 0xFF);
        c += (((w[i]  >> 7) & 0xFF) == 0xFF);
        c += (((fw[i] >> 7) & 0xFF) == 0xFF);
    }
    atomicAdd(&cnt, c);
    __syncthreads();
    if (threadIdx.x == 0) *flag = (cnt >= 2) ? 1u : 0u;  // 1 = f32 inputs
}

// ---------------- x -> internal bf16 copy ----------------
__global__ void cvt_x(const unsigned* __restrict__ flag, const void* __restrict__ xin,
                      u16* __restrict__ XB) {
    int i = blockIdx.x * 256 + threadIdx.x;  // grid covers NN*FD/4
    if (*flag) {
        float4 v = ((const float4*)xin)[i];
        ushort4 r;
        r.x = f2bf(v.x); r.y = f2bf(v.y); r.z = f2bf(v.z); r.w = f2bf(v.w);
        ((ushort4*)XB)[i] = r;
    } else {
        ((ushort4*)XB)[i] = ((const ushort4*)xin)[i];
    }
}

// ---------------- params prep ----------------
__global__ void prep_params(const unsigned* __restrict__ flag,
                            const void* g1, const void* b1, const void* m1, const void* v1, const void* lb1,
                            const void* g2, const void* b2, const void* m2, const void* v2, const void* lb2,
                            const void* g3, const void* b3, const void* m3, const void* v3,
                            const void* a0s, const void* a0d, const void* gb0in,
                            const void* a1s, const void* a1d, const void* gb1in,
                            const void* fb1in, const void* fb2in,
                            float* S1, float* T1, float* S2, float* T2, float* S3, float* T3,
                            u16* A0S, u16* A0D, u16* A1S, u16* A1D,
                            float* GB0, float* GB1, float* FB1, float* FB2) {
    unsigned f = *flag;
    int c = threadIdx.x;  // block 512
    if (c < 256) {
        float s = ldf(g1, c, f) / sqrtf(ldf(v1, c, f) + 1e-5f);
        S1[c] = s; T1[c] = s * (ldf(lb1, c, f) - ldf(m1, c, f)) + ldf(b1, c, f);
        float s2 = ldf(g2, c, f) / sqrtf(ldf(v2, c, f) + 1e-5f);
        S2[c] = s2; T2[c] = s2 * (ldf(lb2, c, f) - ldf(m2, c, f)) + ldf(b2, c, f);
    }
    float s3 = ldf(g3, c, f) / sqrtf(ldf(v3, c, f) + 1e-5f);
    S3[c] = s3; T3[c] = ldf(b3, c, f) - ldf(m3, c, f) * s3;
    A0S[c] = f2bf(ldf(a0s, c, f));
    A0D[c] = f2bf(ldf(a0d, c, f));
    A1S[c] = f2bf(ldf(a1s, c, f));
    A1D[c] = f2bf(ldf(a1d, c, f));
    GB0[c] = ldf(gb0in, c, f);
    GB1[c] = ldf(gb1in, c, f);
    FB1[c] = ldf(fb1in, c, f);
    if (c < NC) FB2[c] = ldf(fb2in, c, f);
}

// ---------------- weight transpose+convert (B[K,N] -> BT[N,K] bf16) ----------------
__global__ void transpose_k(const unsigned* __restrict__ flag, const void* __restrict__ B,
                            u16* __restrict__ BT, int K, int N, int logN) {
    int idx = blockIdx.x * 256 + threadIdx.x;
    if (idx >= K * N) return;
    int k = idx >> logN, n = idx & (N - 1);
    u16 v = (*flag) ? f2bf(((const float*)B)[idx]) : ((const u16*)B)[idx];
    BT[(size_t)n * K + k] = v;
}

// ---------------- CSR build ----------------
__global__ void init_csr(int* deg, int* gcnt) {
    int i = blockIdx.x * 256 + threadIdx.x;
    if (i < NN) deg[i] = 0;
    if (i < NG) gcnt[i] = 0;
}
__global__ void deg_hist(const int* __restrict__ dst, const int* __restrict__ ew, int* __restrict__ deg) {
    int e = blockIdx.x * 256 + threadIdx.x;
    if (e >= EE) return;
    if (ew[e] == 1) atomicAdd(&deg[dst[e]], 1);
}
__global__ void node_hist(const int* __restrict__ batch, int* __restrict__ gcnt) {
    int n = blockIdx.x * 256 + threadIdx.x;
    if (n >= NN) return;
    atomicAdd(&gcnt[batch[n]], 1);
}
// hierarchical scan: (1) per-block local exclusive scan + block totals
__global__ __launch_bounds__(256) void scan_blk(const int* __restrict__ deg, int* __restrict__ off,
                                                int* __restrict__ part) {
    __shared__ int tmp[256];
    int tid = threadIdx.x, i = blockIdx.x * 256 + tid;
    int v = (i < NN) ? deg[i] : 0;
    tmp[tid] = v;
    __syncthreads();
#pragma unroll
    for (int s = 1; s < 256; s <<= 1) {
        int a = (tid >= s) ? tmp[tid - s] : 0;
        __syncthreads();
        if (tid >= s) tmp[tid] += a;
        __syncthreads();
    }
    if (i < NN) off[i] = tmp[tid] - v;   // block-local exclusive
    if (tid == 255) part[blockIdx.x] = tmp[255];
}
// (2) scan the NBLK partials (one small block)
__global__ __launch_bounds__(128) void scan_part(int* __restrict__ part, int* __restrict__ ptot) {
    __shared__ int tmp[128];
    int tid = threadIdx.x;
    int v = (tid < NBLK) ? part[tid] : 0;
    tmp[tid] = v;
    __syncthreads();
#pragma unroll
    for (int s = 1; s < 128; s <<= 1) {
        int a = (tid >= s) ? tmp[tid - s] : 0;
        __syncthreads();
        if (tid >= s) tmp[tid] += a;
        __syncthreads();
    }
    if (tid < NBLK) part[tid] = tmp[tid] - v;  // exclusive
    if (tid == 127) *ptot = tmp[127];
}
// (3) add block prefix, emit cursor copy and total
__global__ __launch_bounds__(256) void scan_add(int* __restrict__ off, const int* __restrict__ part,
                                                const int* __restrict__ ptot, int* __restrict__ cursor) {
    int tid = threadIdx.x, i = blockIdx.x * 256 + tid;
    if (i < NN) {
        int o = off[i] + part[blockIdx.x];
        off[i] = o;
        cursor[i] = o;
    }
    if (i == 0) off[NN] = *ptot;
}
// single-block exclusive scan of gcnt[NG] -> goff[NG+1]
__global__ __launch_bounds__(128) void scan_graphs(const int* __restrict__ gcnt, int* __restrict__ goff) {
    __shared__ int tmp[128];
    int tid = threadIdx.x;
    int v = gcnt[tid];
    tmp[tid] = v;
    __syncthreads();
#pragma unroll
    for (int s = 1; s < 128; s <<= 1) {
        int a = (tid >= s) ? tmp[tid - s] : 0;
        __syncthreads();
        if (tid >= s) tmp[tid] += a;
        __syncthreads();
    }
    goff[tid] = tmp[tid] - v;
    if (tid == 127) goff[128] = tmp[127];
}
__global__ void csr_fill(const int* __restrict__ src, const int* __restrict__ dst, const int* __restrict__ ew,
                         int* __restrict__ cursor, int* __restrict__ csrc) {
    int e = blockIdx.x * 256 + threadIdx.x;
    if (e >= EE) return;
    if (ew[e] != 1) return;
    int p = atomicAdd(&cursor[dst[e]], 1);
    csrc[p] = src[e];
}

// ---------------- MFMA GEMM: C[M,N] = A[M,K] @ B[K,N], BT is B transposed ----------------
// EPI: 0 = store raw bf16, 1 = relu(acc*S[col] + T[col])
template <int EPI>
__global__ __launch_bounds__(256) void gemm_bf16(const u16* __restrict__ A, const u16* __restrict__ BT,
                                                 u16* __restrict__ Cm,
                                                 const float* __restrict__ S, const float* __restrict__ T,
                                                 int M, int N, int K) {
    const int wave = threadIdx.x >> 6;
    const int lane = threadIdx.x & 63;
    const int quad = lane >> 4;
    const int l16  = lane & 15;
    const int row0 = blockIdx.x * 64;
    const int col0 = blockIdx.y * 128 + wave * 32;

    f32x4_t acc[4][2];
#pragma unroll
    for (int r = 0; r < 4; r++)
#pragma unroll
        for (int cb = 0; cb < 2; cb++)
#pragma unroll
            for (int i = 0; i < 4; i++) acc[r][cb][i] = 0.f;

    const u16* ap[4];
#pragma unroll
    for (int r = 0; r < 4; r++) {
        int row = row0 + r * 16 + l16;
        if (row >= M) row = M - 1;  // clamp: loads valid, stores guarded
        ap[r] = A + (size_t)row * K + quad * 8;
    }
    const u16* bp[2];
#pragma unroll
    for (int cb = 0; cb < 2; cb++) {
        int col = col0 + cb * 16 + l16;
        bp[cb] = BT + (size_t)col * K + quad * 8;
    }

    for (int k0 = 0; k0 < K; k0 += 32) {
        bf16x8_t a[4], b[2];
#pragma unroll
        for (int r = 0; r < 4; r++) a[r] = *(const bf16x8_t*)(ap[r] + k0);
#pragma unroll
        for (int cb = 0; cb < 2; cb++) b[cb] = *(const bf16x8_t*)(bp[cb] + k0);
#pragma unroll
        for (int r = 0; r < 4; r++)
#pragma unroll
            for (int cb = 0; cb < 2; cb++)
                acc[r][cb] = __builtin_amdgcn_mfma_f32_16x16x32_bf16(a[r], b[cb], acc[r][cb], 0, 0, 0);
    }

#pragma unroll
    for (int r = 0; r < 4; r++) {
        int row_b = row0 + r * 16 + quad * 4;
#pragma unroll
        for (int cb = 0; cb < 2; cb++) {
            int col = col0 + cb * 16 + l16;
            float sc = (EPI == 1) ? S[col] : 0.f;
            float sh = (EPI == 1) ? T[col] : 0.f;
#pragma unroll
            for (int i = 0; i < 4; i++) {
                int row = row_b + i;
                if (row < M) {
                    float v = acc[r][cb][i];
                    if (EPI == 1) v = fmaxf(v * sc + sh, 0.f);
                    Cm[(size_t)row * N + col] = f2bf(v);
                }
            }
        }
    }
}

// ---------------- GAT: per-node attention logits ----------------
__global__ __launch_bounds__(256) void gat_logits(const u16* __restrict__ xw, const u16* __restrict__ asrc,
                                                  const u16* __restrict__ adst, float* __restrict__ ls,
                                                  float* __restrict__ ld) {
    int n = blockIdx.x * 4 + (threadIdx.x >> 6);
    if (n >= NN) return;
    int lane = threadIdx.x & 63;
    uint4 xv = ((const uint4*)(xw + (size_t)n * C1))[lane];
    uint4 sv = ((const uint4*)asrc)[lane];
    uint4 dv = ((const uint4*)adst)[lane];
    float x[8], a[8], d[8];
    unpack8(xv, x); unpack8(sv, a); unpack8(dv, d);
    float ps = 0.f, pd = 0.f;
#pragma unroll
    for (int j = 0; j < 8; j++) { ps += x[j] * a[j]; pd += x[j] * d[j]; }
#pragma unroll
    for (int m = 16; m >= 1; m >>= 1) { ps += __shfl_xor(ps, m); pd += __shfl_xor(pd, m); }
    if ((lane & 31) == 0) {
        int h = lane >> 5;
        ls[n * 2 + h] = ps;
        ld[n * 2 + h] = pd;
    }
}

// ---------------- fused GAT aggregation: softmax + gather, one wave per node ----------------
// lanes 0..31 -> head 0, lanes 32..63 -> head 1; lane covers features [lane*8, lane*8+8)
__global__ __launch_bounds__(256) void gat_aggregate(const int* __restrict__ off, const int* __restrict__ csrc,
                                                     const float* __restrict__ ls, const float* __restrict__ ld,
                                                     const u16* __restrict__ xw, const float* __restrict__ bias,
                                                     u16* __restrict__ outh) {
    int n = blockIdx.x * 4 + (threadIdx.x >> 6);
    if (n >= NN) return;
    int lane = threadIdx.x & 63;
    int h = lane >> 5;
    int l32 = lane & 31;
    int beg = off[n], end = off[n + 1];
    float ldh = ld[n * 2 + h];

    // pass 1: per-head max over edges (half-wave strided)
    float m = -1e30f;
    for (int i = beg + l32; i < end; i += 32) {
        int s = csrc[i];
        float v = ls[s * 2 + h] + ldh;
        v = v > 0.f ? v : 0.2f * v;
        m = fmaxf(m, v);
    }
#pragma unroll
    for (int o = 16; o >= 1; o >>= 1) m = fmaxf(m, __shfl_xor(m, o));

    // pass 2: per-head sum of exp
    float den = 0.f;
    for (int i = beg + l32; i < end; i += 32) {
        int s = csrc[i];
        float v = ls[s * 2 + h] + ldh;
        v = v > 0.f ? v : 0.2f * v;
        den += __expf(v - m);
    }
#pragma unroll
    for (int o = 16; o >= 1; o >>= 1) den += __shfl_xor(den, o);
    float inv = 1.f / (den + 1e-16f);

    // pass 3: serial edge loop, all lanes gather features
    float acc[8];
#pragma unroll
    for (int j = 0; j < 8; j++) acc[j] = 0.f;
    for (int i = beg; i < end; i++) {
        int s = csrc[i];
        float v = ls[s * 2 + h] + ldh;
        v = v > 0.f ? v : 0.2f * v;
        float alpha = __expf(v - m) * inv;
        uint4 xv = ((const uint4*)(xw + (size_t)s * C1))[lane];
        float x[8];
        unpack8(xv, x);
#pragma unroll
        for (int j = 0; j < 8; j++) acc[j] = fmaf(alpha, x[j], acc[j]);
    }

    ushort4 r0, r1;
    int cb = lane * 8;
    float o0 = acc[0] + bias[cb + 0], o1 = acc[1] + bias[cb + 1];
    float o2 = acc[2] + bias[cb + 2], o3 = acc[3] + bias[cb + 3];
    float o4 = acc[4] + bias[cb + 4], o5 = acc[5] + bias[cb + 5];
    float o6 = acc[6] + bias[cb + 6], o7 = acc[7] + bias[cb + 7];
    r0.x = f2bf(o0); r0.y = f2bf(o1); r0.z = f2bf(o2); r0.w = f2bf(o3);
    r1.x = f2bf(o4); r1.y = f2bf(o5); r1.z = f2bf(o6); r1.w = f2bf(o7);
    ushort4* dst4 = (ushort4*)(outh + (size_t)n * C1 + cb);
    dst4[0] = r0; dst4[1] = r1;
}

// ---------------- fused pool + BN3 + ReLU (block per graph; batch is sorted) ----------------
__global__ __launch_bounds__(512) void pool_bn(const u16* __restrict__ h4, const int* __restrict__ goff,
                                               const float* __restrict__ S3, const float* __restrict__ T3,
                                               u16* __restrict__ z1) {
    int g = blockIdx.x, t = threadIdx.x;
    int b = goff[g], e = goff[g + 1];
    float s = 0.f;
    for (int n = b; n < e; n++) s += bf2f(h4[(size_t)n * C1 + t]);
    float mean = s / fmaxf((float)(e - b), 1.f);
    float v = mean * S3[t] + T3[t];
    z1[(size_t)g * C1 + t] = f2bf(fmaxf(v, 0.f));
}

// ---------------- head ----------------
__global__ __launch_bounds__(512) void head_fc1(const unsigned* __restrict__ flag, const u16* __restrict__ z1,
                                                const void* __restrict__ w1, const float* __restrict__ FB1,
                                                u16* __restrict__ z2) {
    __shared__ float zrow[512];
    int g = blockIdx.x, t = threadIdx.x;
    zrow[t] = bf2f(z1[(size_t)g * 512 + t]);
    __syncthreads();
    float acc = 0.f;
    if (*flag) {
        const float* w = (const float*)w1;
        for (int k = 0; k < 512; k++) acc = fmaf(zrow[k], w[(size_t)k * 512 + t], acc);
    } else {
        const u16* w = (const u16*)w1;
        for (int k = 0; k < 512; k++) acc = fmaf(zrow[k], bf2f(w[(size_t)k * 512 + t]), acc);
    }
    acc += FB1[t];
    z2[(size_t)g * 512 + t] = f2bf(fmaxf(acc, 0.f));
}
__global__ __launch_bounds__(64) void head_fc2(const unsigned* __restrict__ flag, const u16* __restrict__ z2,
                                               const void* __restrict__ w2, const float* __restrict__ FB2,
                                               void* __restrict__ out) {
    int g = blockIdx.x, o = blockIdx.y, lane = threadIdx.x;
    unsigned f = *flag;
    float acc = 0.f;
    if (f) {
        const float* w = (const float*)w2;
        for (int k = lane; k < 512; k += 64) acc += bf2f(z2[(size_t)g * 512 + k]) * w[(size_t)k * NC + o];
    } else {
        const u16* w = (const u16*)w2;
        for (int k = lane; k < 512; k += 64) acc += bf2f(z2[(size_t)g * 512 + k]) * bf2f(w[(size_t)k * NC + o]);
    }
#pragma unroll
    for (int m = 32; m >= 1; m >>= 1) acc += __shfl_xor(acc, m);
    if (lane == 0) {
        float v = acc + FB2[o];
        if (f) ((float*)out)[g * NC + o] = v;
        else   ((u16*)out)[g * NC + o] = f2bf(v);
    }
}

// ---------------- launch ----------------
extern "C" void kernel_launch(void* const* d_in, const int* in_sizes, int n_in,
                              void* d_out, int out_size, void* d_ws, size_t ws_size,
                              hipStream_t stream) {
    (void)in_sizes; (void)n_in; (void)out_size; (void)ws_size;

    const void* x      = d_in[0];
    const int* ei      = (const int*)d_in[1];
    const int* src     = ei;
    const int* dst     = ei + EE;
    const int* ew      = (const int*)d_in[2];
    const int* batch   = (const int*)d_in[3];
    const void* mlp_w1 = d_in[4];
    const void* mlp_b1 = d_in[5];
    const void *bn1g = d_in[6], *bn1b = d_in[7], *bn1m = d_in[8], *bn1v = d_in[9];
    const void* mlp_w2 = d_in[10];
    const void* mlp_b2 = d_in[11];
    const void *bn2g = d_in[12], *bn2b = d_in[13], *bn2m = d_in[14], *bn2v = d_in[15];
    const void* g0w    = d_in[16];
    const void* g0as   = d_in[17];
    const void* g0ad   = d_in[18];
    const void* g0bias = d_in[19];
    const void* g1w    = d_in[20];
    const void* g1as   = d_in[21];
    const void* g1ad   = d_in[22];
    const void* g1bias = d_in[23];
    const void *bn3g = d_in[24], *bn3b = d_in[25], *bn3m = d_in[26], *bn3v = d_in[27];
    const void* fin_w1 = d_in[28];
    const void* fin_b1 = d_in[29];
    const void* fin_w2 = d_in[30];
    const void* fin_b2 = d_in[31];

    char* ws = (char*)d_ws;
    u16*  XB   = (u16*)(ws + OFF_XB);
    u16*  h1   = (u16*)(ws + OFF_H1);
    u16*  h2   = (u16*)(ws + OFF_H2);
    u16*  xw   = (u16*)(ws + OFF_XW);
    u16*  h34  = (u16*)(ws + OFF_H34);
    float* ls  = (float*)(ws + OFF_LS);
    float* ld  = (float*)(ws + OFF_LD);
    int*  deg  = (int*)(ws + OFF_DEG);
    int*  off  = (int*)(ws + OFF_OFFS);
    int*  cur  = (int*)(ws + OFF_CUR);
    int*  csrc = (int*)(ws + OFF_CSRC);
    int*  gcnt = (int*)(ws + OFF_GCNT);
    int*  goff = (int*)(ws + OFF_GOFF);
    int*  part = (int*)(ws + OFF_PART);
    int*  ptot = (int*)(ws + OFF_PTOT);
    u16*  z1   = (u16*)(ws + OFF_Z1);
    u16*  z2   = (u16*)(ws + OFF_Z2);
    float* S1 = (float*)(ws + OFF_ST);
    float* T1 = S1 + 256;
    float* S2 = T1 + 256;
    float* T2 = S2 + 256;
    float* S3 = T2 + 256;
    float* T3 = S3 + 512;
    u16* w1T = (u16*)(ws + OFF_W1T);
    u16* w2T = (u16*)(ws + OFF_W2T);
    u16* g0T = (u16*)(ws + OFF_G0T);
    u16* g1T = (u16*)(ws + OFF_G1T);
    unsigned* flag = (unsigned*)(ws + OFF_FLAG);
    u16* A0S = (u16*)(ws + OFF_A0S);
    u16* A0D = (u16*)(ws + OFF_A0D);
    u16* A1S = (u16*)(ws + OFF_A1S);
    u16* A1D = (u16*)(ws + OFF_A1D);
    float* GB0 = (float*)(ws + OFF_GB0);
    float* GB1 = (float*)(ws + OFF_GB1);
    float* FB1 = (float*)(ws + OFF_FB1);
    float* FB2 = (float*)(ws + OFF_FB2);

    // dtype detection + input normalization
    detect_dtype<<<1, 256, 0, stream>>>((const u16*)x, (const u16*)mlp_w1, (const u16*)fin_w1, flag);
    cvt_x<<<(NN * FD / 4) / 256, 256, 0, stream>>>(flag, x, XB);
    prep_params<<<1, 512, 0, stream>>>(flag,
                                       bn1g, bn1b, bn1m, bn1v, mlp_b1,
                                       bn2g, bn2b, bn2m, bn2v, mlp_b2,
                                       bn3g, bn3b, bn3m, bn3v,
                                       g0as, g0ad, g0bias, g1as, g1ad, g1bias,
                                       fin_b1, fin_b2,
                                       S1, T1, S2, T2, S3, T3,
                                       A0S, A0D, A1S, A1D, GB0, GB1, FB1, FB2);
    transpose_k<<<(FD * C0) / 256, 256, 0, stream>>>(flag, mlp_w1, w1T, FD, C0, 8);
    transpose_k<<<(C0 * C0) / 256, 256, 0, stream>>>(flag, mlp_w2, w2T, C0, C0, 8);
    transpose_k<<<(C0 * C1) / 256, 256, 0, stream>>>(flag, g0w, g0T, C0, C1, 9);
    transpose_k<<<(C1 * C1) / 256, 256, 0, stream>>>(flag, g1w, g1T, C1, C1, 9);

    // CSR build (graph fixed across both layers) + graph offsets
    init_csr<<<NBLK, 256, 0, stream>>>(deg, gcnt);
    deg_hist<<<EE / 256, 256, 0, stream>>>(dst, ew, deg);
    node_hist<<<NBLK, 256, 0, stream>>>(batch, gcnt);
    scan_blk<<<NBLK, 256, 0, stream>>>(deg, off, part);
    scan_part<<<1, 128, 0, stream>>>(part, ptot);
    scan_add<<<NBLK, 256, 0, stream>>>(off, part, ptot, cur);
    scan_graphs<<<1, 128, 0, stream>>>(gcnt, goff);
    csr_fill<<<EE / 256, 256, 0, stream>>>(src, dst, ew, cur, csrc);

    // MLP
    gemm_bf16<1><<<dim3(313, 2), 256, 0, stream>>>(XB, w1T, h1, S1, T1, NN, C0, FD);
    gemm_bf16<1><<<dim3(313, 2), 256, 0, stream>>>(h1, w2T, h2, S2, T2, NN, C0, C0);

    // GAT layer 0
    gemm_bf16<0><<<dim3(313, 4), 256, 0, stream>>>(h2, g0T, xw, nullptr, nullptr, NN, C1, C0);
    gat_logits<<<NN / 4, 256, 0, stream>>>(xw, A0S, A0D, ls, ld);
    gat_aggregate<<<NN / 4, 256, 0, stream>>>(off, csrc, ls, ld, xw, GB0, h34);

    // GAT layer 1
    gemm_bf16<0><<<dim3(313, 4), 256, 0, stream>>>(h34, g1T, xw, nullptr, nullptr, NN, C1, C1);
    gat_logits<<<NN / 4, 256, 0, stream>>>(xw, A1S, A1D, ls, ld);
    gat_aggregate<<<NN / 4, 256, 0, stream>>>(off, csrc, ls, ld, xw, GB1, h34);  // h4

    // pool + head
    pool_bn<<<NG, 512, 0, stream>>>(h34, goff, S3, T3, z1);
    head_fc1<<<NG, 512, 0, stream>>>(flag, z1, fin_w1, FB1, z2);
    head_fc2<<<dim3(NG, NC), 64, 0, stream>>>(flag, z2, fin_w2, FB2, d_out);
}

// Round 5
// 491.708 us; speedup vs baseline: 19.3431x; 1.1063x over previous
//
#include <hip/hip_runtime.h>

typedef unsigned short u16;

// ---------------- problem constants ----------------
constexpr int NN = 20000;   // nodes
constexpr int EE = 320000;  // edges
constexpr int FD = 128;     // input features
constexpr int C0 = 256;     // hidden (mlp)
constexpr int C1 = 512;     // H*C for GAT
constexpr int NG = 128;     // graphs
constexpr int NC = 10;      // classes
constexpr int NBLK = (NN + 255) / 256;  // 79

// ---------------- workspace layout (bytes) ----------------
constexpr size_t OFF_XB   = 0;                                   // NN*FD bf16
constexpr size_t OFF_H1   = OFF_XB  + (size_t)NN * FD * 2;       // NN*C0 bf16
constexpr size_t OFF_H2   = OFF_H1  + (size_t)NN * C0 * 2;       // NN*C0 bf16
constexpr size_t OFF_XW   = OFF_H2  + (size_t)NN * C0 * 2;       // NN*C1 bf16
constexpr size_t OFF_H34  = OFF_XW  + (size_t)NN * C1 * 2;       // NN*C1 bf16 (h3 then h4)
constexpr size_t OFF_LS   = OFF_H34 + (size_t)NN * C1 * 2;       // NN*2 f32
constexpr size_t OFF_LD   = OFF_LS  + (size_t)NN * 2 * 4;        // NN*2 f32
constexpr size_t OFF_DEG  = OFF_LD  + (size_t)NN * 2 * 4;        // NN i32
constexpr size_t OFF_OFFS = OFF_DEG + (size_t)NN * 4;            // NN+1 i32 (pad 80016)
constexpr size_t OFF_CUR  = OFF_OFFS + 80016;                    // NN i32
constexpr size_t OFF_CSRC = OFF_CUR + (size_t)NN * 4;            // EE i32
constexpr size_t OFF_GCNT = OFF_CSRC + (size_t)EE * 4;           // NG i32
constexpr size_t OFF_GOFF = OFF_GCNT + 512;                      // NG+1 i32 (pad 768)
constexpr size_t OFF_PART = OFF_GOFF + 768;                      // NBLK i32 (pad 512)
constexpr size_t OFF_PTOT = OFF_PART + 512;                      // 1 i32 (pad 256)
constexpr size_t OFF_Z1   = OFF_PTOT + 256;                      // NG*C1 bf16
constexpr size_t OFF_Z2   = OFF_Z1  + (size_t)NG * C1 * 2;
constexpr size_t OFF_ST   = OFF_Z2  + (size_t)NG * C1 * 2;       // S1,T1,S2,T2 (256 f32), S3,T3 (512 f32)
constexpr size_t OFF_W1T  = OFF_ST  + 8192;
constexpr size_t OFF_W2T  = OFF_W1T + (size_t)FD * C0 * 2;
constexpr size_t OFF_G0T  = OFF_W2T + (size_t)C0 * C0 * 2;
constexpr size_t OFF_G1T  = OFF_G0T + (size_t)C0 * C1 * 2;
constexpr size_t OFF_AUX  = OFF_G1T + (size_t)C1 * C1 * 2;
constexpr size_t OFF_FLAG = OFF_AUX  + 0;      // u32
constexpr size_t OFF_A0S  = OFF_AUX  + 256;    // 512 u16
constexpr size_t OFF_A0D  = OFF_AUX  + 1280;
constexpr size_t OFF_A1S  = OFF_AUX  + 2304;
constexpr size_t OFF_A1D  = OFF_AUX  + 3328;
constexpr size_t OFF_GB0  = OFF_AUX  + 4352;   // 512 f32
constexpr size_t OFF_GB1  = OFF_AUX  + 6400;
constexpr size_t OFF_FB1  = OFF_AUX  + 8448;   // 512 f32
constexpr size_t OFF_FB2  = OFF_AUX  + 10496;  // 10 f32
// end ~= 70 MB

// ---------------- helpers ----------------
__device__ inline float bf2f(u16 u) { return __uint_as_float(((unsigned)u) << 16); }
__device__ inline u16 f2bf(float f) {
    unsigned u = __float_as_uint(f);
    unsigned r = u + 0x7fffu + ((u >> 16) & 1u);   // RNE
    return (u16)(r >> 16);
}
// flag-driven load of an external float input (flag=1 -> f32, 0 -> bf16)
__device__ inline float ldf(const void* p, long i, unsigned f) {
    return f ? ((const float*)p)[i] : bf2f(((const u16*)p)[i]);
}
__device__ inline void unpack8(uint4 r, float* v) {
    v[0] = bf2f((u16)(r.x & 0xffff)); v[1] = bf2f((u16)(r.x >> 16));
    v[2] = bf2f((u16)(r.y & 0xffff)); v[3] = bf2f((u16)(r.y >> 16));
    v[4] = bf2f((u16)(r.z & 0xffff)); v[5] = bf2f((u16)(r.z >> 16));
    v[6] = bf2f((u16)(r.w & 0xffff)); v[7] = bf2f((u16)(r.w >> 16));
}

typedef __bf16 bf16x8_t __attribute__((ext_vector_type(8)));
typedef float  f32x4_t  __attribute__((ext_vector_type(4)));

// async 16B global -> LDS (wave-uniform LDS base + lane*16 layout)
__device__ __forceinline__ void gl_lds16(const u16* g, u16* l) {
    __builtin_amdgcn_global_load_lds((const __attribute__((address_space(1))) void*)g,
                                     (__attribute__((address_space(3))) void*)l, 16, 0, 0);
}

// ---------------- dtype detector ----------------
__global__ void detect_dtype(const u16* __restrict__ x, const u16* __restrict__ w,
                             const u16* __restrict__ fw, unsigned* flag) {
    __shared__ int cnt;
    if (threadIdx.x == 0) cnt = 0;
    __syncthreads();
    int c = 0;
    for (int i = threadIdx.x; i < 4096; i += 256) {
        c += (((x[i]  >> 7) & 0xFF) == 0xFF);
        c += (((w[i]  >> 7) & 0xFF) == 0xFF);
        c += (((fw[i] >> 7) & 0xFF) == 0xFF);
    }
    atomicAdd(&cnt, c);
    __syncthreads();
    if (threadIdx.x == 0) *flag = (cnt >= 2) ? 1u : 0u;  // 1 = f32 inputs
}

// ---------------- x -> internal bf16 copy ----------------
__global__ void cvt_x(const unsigned* __restrict__ flag, const void* __restrict__ xin,
                      u16* __restrict__ XB) {
    int i = blockIdx.x * 256 + threadIdx.x;  // grid covers NN*FD/4
    if (*flag) {
        float4 v = ((const float4*)xin)[i];
        ushort4 r;
        r.x = f2bf(v.x); r.y = f2bf(v.y); r.z = f2bf(v.z); r.w = f2bf(v.w);
        ((ushort4*)XB)[i] = r;
    } else {
        ((ushort4*)XB)[i] = ((const ushort4*)xin)[i];
    }
}

// ---------------- params prep ----------------
__global__ void prep_params(const unsigned* __restrict__ flag,
                            const void* g1, const void* b1, const void* m1, const void* v1, const void* lb1,
                            const void* g2, const void* b2, const void* m2, const void* v2, const void* lb2,
                            const void* g3, const void* b3, const void* m3, const void* v3,
                            const void* a0s, const void* a0d, const void* gb0in,
                            const void* a1s, const void* a1d, const void* gb1in,
                            const void* fb1in, const void* fb2in,
                            float* S1, float* T1, float* S2, float* T2, float* S3, float* T3,
                            u16* A0S, u16* A0D, u16* A1S, u16* A1D,
                            float* GB0, float* GB1, float* FB1, float* FB2) {
    unsigned f = *flag;
    int c = threadIdx.x;  // block 512
    if (c < 256) {
        float s = ldf(g1, c, f) / sqrtf(ldf(v1, c, f) + 1e-5f);
        S1[c] = s; T1[c] = s * (ldf(lb1, c, f) - ldf(m1, c, f)) + ldf(b1, c, f);
        float s2 = ldf(g2, c, f) / sqrtf(ldf(v2, c, f) + 1e-5f);
        S2[c] = s2; T2[c] = s2 * (ldf(lb2, c, f) - ldf(m2, c, f)) + ldf(b2, c, f);
    }
    float s3 = ldf(g3, c, f) / sqrtf(ldf(v3, c, f) + 1e-5f);
    S3[c] = s3; T3[c] = ldf(b3, c, f) - ldf(m3, c, f) * s3;
    A0S[c] = f2bf(ldf(a0s, c, f));
    A0D[c] = f2bf(ldf(a0d, c, f));
    A1S[c] = f2bf(ldf(a1s, c, f));
    A1D[c] = f2bf(ldf(a1d, c, f));
    GB0[c] = ldf(gb0in, c, f);
    GB1[c] = ldf(gb1in, c, f);
    FB1[c] = ldf(fb1in, c, f);
    if (c < NC) FB2[c] = ldf(fb2in, c, f);
}

// ---------------- weight transpose+convert (B[K,N] -> BT[N,K] bf16) ----------------
__global__ void transpose_k(const unsigned* __restrict__ flag, const void* __restrict__ B,
                            u16* __restrict__ BT, int K, int N, int logN) {
    int idx = blockIdx.x * 256 + threadIdx.x;
    if (idx >= K * N) return;
    int k = idx >> logN, n = idx & (N - 1);
    u16 v = (*flag) ? f2bf(((const float*)B)[idx]) : ((const u16*)B)[idx];
    BT[(size_t)n * K + k] = v;
}

// ---------------- CSR build ----------------
__global__ void init_csr(int* deg, int* gcnt) {
    int i = blockIdx.x * 256 + threadIdx.x;
    if (i < NN) deg[i] = 0;
    if (i < NG) gcnt[i] = 0;
}
__global__ void deg_hist(const int* __restrict__ dst, const int* __restrict__ ew, int* __restrict__ deg) {
    int e = blockIdx.x * 256 + threadIdx.x;
    if (e >= EE) return;
    if (ew[e] == 1) atomicAdd(&deg[dst[e]], 1);
}
__global__ void node_hist(const int* __restrict__ batch, int* __restrict__ gcnt) {
    int n = blockIdx.x * 256 + threadIdx.x;
    if (n >= NN) return;
    atomicAdd(&gcnt[batch[n]], 1);
}
// hierarchical scan: (1) per-block local exclusive scan + block totals
__global__ __launch_bounds__(256) void scan_blk(const int* __restrict__ deg, int* __restrict__ off,
                                                int* __restrict__ part) {
    __shared__ int tmp[256];
    int tid = threadIdx.x, i = blockIdx.x * 256 + tid;
    int v = (i < NN) ? deg[i] : 0;
    tmp[tid] = v;
    __syncthreads();
#pragma unroll
    for (int s = 1; s < 256; s <<= 1) {
        int a = (tid >= s) ? tmp[tid - s] : 0;
        __syncthreads();
        if (tid >= s) tmp[tid] += a;
        __syncthreads();
    }
    if (i < NN) off[i] = tmp[tid] - v;   // block-local exclusive
    if (tid == 255) part[blockIdx.x] = tmp[255];
}
// (2) scan the NBLK partials (one small block)
__global__ __launch_bounds__(128) void scan_part(int* __restrict__ part, int* __restrict__ ptot) {
    __shared__ int tmp[128];
    int tid = threadIdx.x;
    int v = (tid < NBLK) ? part[tid] : 0;
    tmp[tid] = v;
    __syncthreads();
#pragma unroll
    for (int s = 1; s < 128; s <<= 1) {
        int a = (tid >= s) ? tmp[tid - s] : 0;
        __syncthreads();
        if (tid >= s) tmp[tid] += a;
        __syncthreads();
    }
    if (tid < NBLK) part[tid] = tmp[tid] - v;  // exclusive
    if (tid == 127) *ptot = tmp[127];
}
// (3) add block prefix, emit cursor copy and total
__global__ __launch_bounds__(256) void scan_add(int* __restrict__ off, const int* __restrict__ part,
                                                const int* __restrict__ ptot, int* __restrict__ cursor) {
    int tid = threadIdx.x, i = blockIdx.x * 256 + tid;
    if (i < NN) {
        int o = off[i] + part[blockIdx.x];
        off[i] = o;
        cursor[i] = o;
    }
    if (i == 0) off[NN] = *ptot;
}
// single-block exclusive scan of gcnt[NG] -> goff[NG+1]
__global__ __launch_bounds__(128) void scan_graphs(const int* __restrict__ gcnt, int* __restrict__ goff) {
    __shared__ int tmp[128];
    int tid = threadIdx.x;
    int v = gcnt[tid];
    tmp[tid] = v;
    __syncthreads();
#pragma unroll
    for (int s = 1; s < 128; s <<= 1) {
        int a = (tid >= s) ? tmp[tid - s] : 0;
        __syncthreads();
        if (tid >= s) tmp[tid] += a;
        __syncthreads();
    }
    goff[tid] = tmp[tid] - v;
    if (tid == 127) goff[128] = tmp[127];
}
__global__ void csr_fill(const int* __restrict__ src, const int* __restrict__ dst, const int* __restrict__ ew,
                         int* __restrict__ cursor, int* __restrict__ csrc) {
    int e = blockIdx.x * 256 + threadIdx.x;
    if (e >= EE) return;
    if (ew[e] != 1) return;
    int p = atomicAdd(&cursor[dst[e]], 1);
    csrc[p] = src[e];
}

// ---------------- MFMA GEMM (m97-style LDS-staged): C[M,N] = A[M,K] @ B[K,N] ----------------
// 128x128 block, 4 waves 2x2 (64x64 per wave), BK=32, async global->LDS staging.
// EPI: 0 = store raw bf16, 1 = relu(acc*S[col] + T[col])
template <int EPI>
__global__ __launch_bounds__(256) void gemm_tile(const u16* __restrict__ A, const u16* __restrict__ BT,
                                                 u16* __restrict__ Cm,
                                                 const float* __restrict__ S, const float* __restrict__ T,
                                                 int M, int N, int K) {
    __shared__ u16 As[128 * 32];   // [row][k] row-major, unpadded (global_load_lds layout)
    __shared__ u16 Bs[128 * 32];   // [col][k]
    const int tid  = threadIdx.x;
    const int wave = tid >> 6;
    const int lane = tid & 63;
    const int quad = lane >> 4;
    const int l16  = lane & 15;
    const int wr0  = (wave >> 1) * 64;
    const int wc0  = (wave & 1) * 64;
    const int row0 = blockIdx.x * 128;
    const int col0 = blockIdx.y * 128;

    // staging addressing: each wave stages 32 A-rows + 32 B-cols per K-step,
    // as 2+2 instructions of 16 rows x (16B = 8 elems) each.
    const int lr = lane >> 2;          // 0..15 row within 16-row segment
    const int lk = (lane & 3) * 8;     // 0,8,16,24 element offset in k
    int r0l = wave * 32 + lr;
    int r1l = r0l + 16;
    int gr0 = row0 + r0l; if (gr0 >= M) gr0 = M - 1;   // clamp: loads valid, stores guarded
    int gr1 = row0 + r1l; if (gr1 >= M) gr1 = M - 1;
    const u16* ga0 = A  + (size_t)gr0 * K + lk;
    const u16* ga1 = A  + (size_t)gr1 * K + lk;
    const u16* gb0 = BT + (size_t)(col0 + r0l) * K + lk;
    const u16* gb1 = BT + (size_t)(col0 + r1l) * K + lk;
    u16* la0 = As + (size_t)(wave * 32)      * 32 + lane * 8;
    u16* la1 = As + (size_t)(wave * 32 + 16) * 32 + lane * 8;
    u16* lb0 = Bs + (size_t)(wave * 32)      * 32 + lane * 8;
    u16* lb1 = Bs + (size_t)(wave * 32 + 16) * 32 + lane * 8;

    f32x4_t acc[4][4];
#pragma unroll
    for (int r = 0; r < 4; r++)
#pragma unroll
        for (int c = 0; c < 4; c++)
#pragma unroll
            for (int i = 0; i < 4; i++) acc[r][c][i] = 0.f;

    for (int k0 = 0; k0 < K; k0 += 32) {
        gl_lds16(ga0 + k0, la0);
        gl_lds16(ga1 + k0, la1);
        gl_lds16(gb0 + k0, lb0);
        gl_lds16(gb1 + k0, lb1);
        __syncthreads();   // drains vmcnt (async LDS writes) + all waves

        bf16x8_t a[4], b[4];
#pragma unroll
        for (int r = 0; r < 4; r++)
            a[r] = *(const bf16x8_t*)(As + (size_t)(wr0 + r * 16 + l16) * 32 + quad * 8);
#pragma unroll
        for (int c = 0; c < 4; c++)
            b[c] = *(const bf16x8_t*)(Bs + (size_t)(wc0 + c * 16 + l16) * 32 + quad * 8);
#pragma unroll
        for (int r = 0; r < 4; r++)
#pragma unroll
            for (int c = 0; c < 4; c++)
                acc[r][c] = __builtin_amdgcn_mfma_f32_16x16x32_bf16(a[r], b[c], acc[r][c], 0, 0, 0);
        __syncthreads();   // LDS reads done before next staging overwrites
    }

#pragma unroll
    for (int r = 0; r < 4; r++) {
        int rb = row0 + wr0 + r * 16 + quad * 4;
#pragma unroll
        for (int c = 0; c < 4; c++) {
            int col = col0 + wc0 + c * 16 + l16;
            float sc = (EPI == 1) ? S[col] : 0.f;
            float sh = (EPI == 1) ? T[col] : 0.f;
#pragma unroll
            for (int i = 0; i < 4; i++) {
                int row = rb + i;
                if (row < M) {
                    float v = acc[r][c][i];
                    if (EPI == 1) v = fmaxf(v * sc + sh, 0.f);
                    Cm[(size_t)row * N + col] = f2bf(v);
                }
            }
        }
    }
}

// ---------------- GAT: per-node attention logits ----------------
__global__ __launch_bounds__(256) void gat_logits(const u16* __restrict__ xw, const u16* __restrict__ asrc,
                                                  const u16* __restrict__ adst, float* __restrict__ ls,
                                                  float* __restrict__ ld) {
    int n = blockIdx.x * 4 + (threadIdx.x >> 6);
    if (n >= NN) return;
    int lane = threadIdx.x & 63;
    uint4 xv = ((const uint4*)(xw + (size_t)n * C1))[lane];
    uint4 sv = ((const uint4*)asrc)[lane];
    uint4 dv = ((const uint4*)adst)[lane];
    float x[8], a[8], d[8];
    unpack8(xv, x); unpack8(sv, a); unpack8(dv, d);
    float ps = 0.f, pd = 0.f;
#pragma unroll
    for (int j = 0; j < 8; j++) { ps += x[j] * a[j]; pd += x[j] * d[j]; }
#pragma unroll
    for (int m = 16; m >= 1; m >>= 1) { ps += __shfl_xor(ps, m); pd += __shfl_xor(pd, m); }
    if ((lane & 31) == 0) {
        int h = lane >> 5;
        ls[n * 2 + h] = ps;
        ld[n * 2 + h] = pd;
    }
}

// ---------------- fused GAT aggregation: softmax + gather, one wave per node ----------------
// lanes 0..31 -> head 0, lanes 32..63 -> head 1; lane covers features [lane*8, lane*8+8)
__global__ __launch_bounds__(256) void gat_aggregate(const int* __restrict__ off, const int* __restrict__ csrc,
                                                     const float* __restrict__ ls, const float* __restrict__ ld,
                                                     const u16* __restrict__ xw, const float* __restrict__ bias,
                                                     u16* __restrict__ outh) {
    int n = blockIdx.x * 4 + (threadIdx.x >> 6);
    if (n >= NN) return;
    int lane = threadIdx.x & 63;
    int h = lane >> 5;
    int l32 = lane & 31;
    int beg = off[n], end = off[n + 1];
    float ldh = ld[n * 2 + h];

    // pass 1: per-head max over edges (half-wave strided)
    float m = -1e30f;
    for (int i = beg + l32; i < end; i += 32) {
        int s = csrc[i];
        float v = ls[s * 2 + h] + ldh;
        v = v > 0.f ? v : 0.2f * v;
        m = fmaxf(m, v);
    }
#pragma unroll
    for (int o = 16; o >= 1; o >>= 1) m = fmaxf(m, __shfl_xor(m, o));

    // pass 2: per-head sum of exp
    float den = 0.f;
    for (int i = beg + l32; i < end; i += 32) {
        int s = csrc[i];
        float v = ls[s * 2 + h] + ldh;
        v = v > 0.f ? v : 0.2f * v;
        den += __expf(v - m);
    }
#pragma unroll
    for (int o = 16; o >= 1; o >>= 1) den += __shfl_xor(den, o);
    float inv = 1.f / (den + 1e-16f);

    // pass 3: serial edge loop, all lanes gather features
    float acc[8];
#pragma unroll
    for (int j = 0; j < 8; j++) acc[j] = 0.f;
    for (int i = beg; i < end; i++) {
        int s = csrc[i];
        float v = ls[s * 2 + h] + ldh;
        v = v > 0.f ? v : 0.2f * v;
        float alpha = __expf(v - m) * inv;
        uint4 xv = ((const uint4*)(xw + (size_t)s * C1))[lane];
        float x[8];
        unpack8(xv, x);
#pragma unroll
        for (int j = 0; j < 8; j++) acc[j] = fmaf(alpha, x[j], acc[j]);
    }

    ushort4 r0, r1;
    int cb = lane * 8;
    float o0 = acc[0] + bias[cb + 0], o1 = acc[1] + bias[cb + 1];
    float o2 = acc[2] + bias[cb + 2], o3 = acc[3] + bias[cb + 3];
    float o4 = acc[4] + bias[cb + 4], o5 = acc[5] + bias[cb + 5];
    float o6 = acc[6] + bias[cb + 6], o7 = acc[7] + bias[cb + 7];
    r0.x = f2bf(o0); r0.y = f2bf(o1); r0.z = f2bf(o2); r0.w = f2bf(o3);
    r1.x = f2bf(o4); r1.y = f2bf(o5); r1.z = f2bf(o6); r1.w = f2bf(o7);
    ushort4* dst4 = (ushort4*)(outh + (size_t)n * C1 + cb);
    dst4[0] = r0; dst4[1] = r1;
}

// ---------------- fused pool + BN3 + ReLU (block per graph; batch is sorted) ----------------
__global__ __launch_bounds__(512) void pool_bn(const u16* __restrict__ h4, const int* __restrict__ goff,
                                               const float* __restrict__ S3, const float* __restrict__ T3,
                                               u16* __restrict__ z1) {
    int g = blockIdx.x, t = threadIdx.x;
    int b = goff[g], e = goff[g + 1];
    float s = 0.f;
    for (int n = b; n < e; n++) s += bf2f(h4[(size_t)n * C1 + t]);
    float mean = s / fmaxf((float)(e - b), 1.f);
    float v = mean * S3[t] + T3[t];
    z1[(size_t)g * C1 + t] = f2bf(fmaxf(v, 0.f));
}

// ---------------- head ----------------
__global__ __launch_bounds__(512) void head_fc1(const unsigned* __restrict__ flag, const u16* __restrict__ z1,
                                                const void* __restrict__ w1, const float* __restrict__ FB1,
                                                u16* __restrict__ z2) {
    __shared__ float zrow[512];
    int g = blockIdx.x, t = threadIdx.x;
    zrow[t] = bf2f(z1[(size_t)g * 512 + t]);
    __syncthreads();
    float acc = 0.f;
    if (*flag) {
        const float* w = (const float*)w1;
        for (int k = 0; k < 512; k++) acc = fmaf(zrow[k], w[(size_t)k * 512 + t], acc);
    } else {
        const u16* w = (const u16*)w1;
        for (int k = 0; k < 512; k++) acc = fmaf(zrow[k], bf2f(w[(size_t)k * 512 + t]), acc);
    }
    acc += FB1[t];
    z2[(size_t)g * 512 + t] = f2bf(fmaxf(acc, 0.f));
}
__global__ __launch_bounds__(64) void head_fc2(const unsigned* __restrict__ flag, const u16* __restrict__ z2,
                                               const void* __restrict__ w2, const float* __restrict__ FB2,
                                               void* __restrict__ out) {
    int g = blockIdx.x, o = blockIdx.y, lane = threadIdx.x;
    unsigned f = *flag;
    float acc = 0.f;
    if (f) {
        const float* w = (const float*)w2;
        for (int k = lane; k < 512; k += 64) acc += bf2f(z2[(size_t)g * 512 + k]) * w[(size_t)k * NC + o];
    } else {
        const u16* w = (const u16*)w2;
        for (int k = lane; k < 512; k += 64) acc += bf2f(z2[(size_t)g * 512 + k]) * bf2f(w[(size_t)k * NC + o]);
    }
#pragma unroll
    for (int m = 32; m >= 1; m >>= 1) acc += __shfl_xor(acc, m);
    if (lane == 0) {
        float v = acc + FB2[o];
        if (f) ((float*)out)[g * NC + o] = v;
        else   ((u16*)out)[g * NC + o] = f2bf(v);
    }
}

// ---------------- launch ----------------
extern "C" void kernel_launch(void* const* d_in, const int* in_sizes, int n_in,
                              void* d_out, int out_size, void* d_ws, size_t ws_size,
                              hipStream_t stream) {
    (void)in_sizes; (void)n_in; (void)out_size; (void)ws_size;

    const void* x      = d_in[0];
    const int* ei      = (const int*)d_in[1];
    const int* src     = ei;
    const int* dst     = ei + EE;
    const int* ew      = (const int*)d_in[2];
    const int* batch   = (const int*)d_in[3];
    const void* mlp_w1 = d_in[4];
    const void* mlp_b1 = d_in[5];
    const void *bn1g = d_in[6], *bn1b = d_in[7], *bn1m = d_in[8], *bn1v = d_in[9];
    const void* mlp_w2 = d_in[10];
    const void* mlp_b2 = d_in[11];
    const void *bn2g = d_in[12], *bn2b = d_in[13], *bn2m = d_in[14], *bn2v = d_in[15];
    const void* g0w    = d_in[16];
    const void* g0as   = d_in[17];
    const void* g0ad   = d_in[18];
    const void* g0bias = d_in[19];
    const void* g1w    = d_in[20];
    const void* g1as   = d_in[21];
    const void* g1ad   = d_in[22];
    const void* g1bias = d_in[23];
    const void *bn3g = d_in[24], *bn3b = d_in[25], *bn3m = d_in[26], *bn3v = d_in[27];
    const void* fin_w1 = d_in[28];
    const void* fin_b1 = d_in[29];
    const void* fin_w2 = d_in[30];
    const void* fin_b2 = d_in[31];

    char* ws = (char*)d_ws;
    u16*  XB   = (u16*)(ws + OFF_XB);
    u16*  h1   = (u16*)(ws + OFF_H1);
    u16*  h2   = (u16*)(ws + OFF_H2);
    u16*  xw   = (u16*)(ws + OFF_XW);
    u16*  h34  = (u16*)(ws + OFF_H34);
    float* ls  = (float*)(ws + OFF_LS);
    float* ld  = (float*)(ws + OFF_LD);
    int*  deg  = (int*)(ws + OFF_DEG);
    int*  off  = (int*)(ws + OFF_OFFS);
    int*  cur  = (int*)(ws + OFF_CUR);
    int*  csrc = (int*)(ws + OFF_CSRC);
    int*  gcnt = (int*)(ws + OFF_GCNT);
    int*  goff = (int*)(ws + OFF_GOFF);
    int*  part = (int*)(ws + OFF_PART);
    int*  ptot = (int*)(ws + OFF_PTOT);
    u16*  z1   = (u16*)(ws + OFF_Z1);
    u16*  z2   = (u16*)(ws + OFF_Z2);
    float* S1 = (float*)(ws + OFF_ST);
    float* T1 = S1 + 256;
    float* S2 = T1 + 256;
    float* T2 = S2 + 256;
    float* S3 = T2 + 256;
    float* T3 = S3 + 512;
    u16* w1T = (u16*)(ws + OFF_W1T);
    u16* w2T = (u16*)(ws + OFF_W2T);
    u16* g0T = (u16*)(ws + OFF_G0T);
    u16* g1T = (u16*)(ws + OFF_G1T);
    unsigned* flag = (unsigned*)(ws + OFF_FLAG);
    u16* A0S = (u16*)(ws + OFF_A0S);
    u16* A0D = (u16*)(ws + OFF_A0D);
    u16* A1S = (u16*)(ws + OFF_A1S);
    u16* A1D = (u16*)(ws + OFF_A1D);
    float* GB0 = (float*)(ws + OFF_GB0);
    float* GB1 = (float*)(ws + OFF_GB1);
    float* FB1 = (float*)(ws + OFF_FB1);
    float* FB2 = (float*)(ws + OFF_FB2);

    // dtype detection + input normalization
    detect_dtype<<<1, 256, 0, stream>>>((const u16*)x, (const u16*)mlp_w1, (const u16*)fin_w1, flag);
    cvt_x<<<(NN * FD / 4) / 256, 256, 0, stream>>>(flag, x, XB);
    prep_params<<<1, 512, 0, stream>>>(flag,
                                       bn1g, bn1b, bn1m, bn1v, mlp_b1,
                                       bn2g, bn2b, bn2m, bn2v, mlp_b2,
                                       bn3g, bn3b, bn3m, bn3v,
                                       g0as, g0ad, g0bias, g1as, g1ad, g1bias,
                                       fin_b1, fin_b2,
                                       S1, T1, S2, T2, S3, T3,
                                       A0S, A0D, A1S, A1D, GB0, GB1, FB1, FB2);
    transpose_k<<<(FD * C0) / 256, 256, 0, stream>>>(flag, mlp_w1, w1T, FD, C0, 8);
    transpose_k<<<(C0 * C0) / 256, 256, 0, stream>>>(flag, mlp_w2, w2T, C0, C0, 8);
    transpose_k<<<(C0 * C1) / 256, 256, 0, stream>>>(flag, g0w, g0T, C0, C1, 9);
    transpose_k<<<(C1 * C1) / 256, 256, 0, stream>>>(flag, g1w, g1T, C1, C1, 9);

    // CSR build (graph fixed across both layers) + graph offsets
    init_csr<<<NBLK, 256, 0, stream>>>(deg, gcnt);
    deg_hist<<<EE / 256, 256, 0, stream>>>(dst, ew, deg);
    node_hist<<<NBLK, 256, 0, stream>>>(batch, gcnt);
    scan_blk<<<NBLK, 256, 0, stream>>>(deg, off, part);
    scan_part<<<1, 128, 0, stream>>>(part, ptot);
    scan_add<<<NBLK, 256, 0, stream>>>(off, part, ptot, cur);
    scan_graphs<<<1, 128, 0, stream>>>(gcnt, goff);
    csr_fill<<<EE / 256, 256, 0, stream>>>(src, dst, ew, cur, csrc);

    // MLP (157 row-blocks of 128 cover 20096 >= 20000)
    gemm_tile<1><<<dim3(157, 2), 256, 0, stream>>>(XB, w1T, h1, S1, T1, NN, C0, FD);
    gemm_tile<1><<<dim3(157, 2), 256, 0, stream>>>(h1, w2T, h2, S2, T2, NN, C0, C0);

    // GAT layer 0
    gemm_tile<0><<<dim3(157, 4), 256, 0, stream>>>(h2, g0T, xw, nullptr, nullptr, NN, C1, C0);
    gat_logits<<<NN / 4, 256, 0, stream>>>(xw, A0S, A0D, ls, ld);
    gat_aggregate<<<NN / 4, 256, 0, stream>>>(off, csrc, ls, ld, xw, GB0, h34);

    // GAT layer 1
    gemm_tile<0><<<dim3(157, 4), 256, 0, stream>>>(h34, g1T, xw, nullptr, nullptr, NN, C1, C1);
    gat_logits<<<NN / 4, 256, 0, stream>>>(xw, A1S, A1D, ls, ld);
    gat_aggregate<<<NN / 4, 256, 0, stream>>>(off, csrc, ls, ld, xw, GB1, h34);  // h4

    // pool + head
    pool_bn<<<NG, 512, 0, stream>>>(h34, goff, S3, T3, z1);
    head_fc1<<<NG, 512, 0, stream>>>(flag, z1, fin_w1, FB1, z2);
    head_fc2<<<dim3(NG, NC), 64, 0, stream>>>(flag, z2, fin_w2, FB2, d_out);
}

// Round 6
// 480.946 us; speedup vs baseline: 19.7759x; 1.0224x over previous
//
#include <hip/hip_runtime.h>

typedef unsigned short u16;

// ---------------- problem constants ----------------
constexpr int NN = 20000;   // nodes
constexpr int EE = 320000;  // edges
constexpr int FD = 128;     // input features
constexpr int C0 = 256;     // hidden (mlp)
constexpr int C1 = 512;     // H*C for GAT
constexpr int NG = 128;     // graphs
constexpr int NC = 10;      // classes
constexpr int NBLK = (NN + 255) / 256;  // 79

// ---------------- workspace layout (bytes) ----------------
constexpr size_t OFF_XB   = 0;                                   // NN*FD bf16
constexpr size_t OFF_H1   = OFF_XB  + (size_t)NN * FD * 2;       // NN*C0 bf16
constexpr size_t OFF_H2   = OFF_H1  + (size_t)NN * C0 * 2;       // NN*C0 bf16
constexpr size_t OFF_XW   = OFF_H2  + (size_t)NN * C0 * 2;       // NN*C1 bf16
constexpr size_t OFF_H34  = OFF_XW  + (size_t)NN * C1 * 2;       // NN*C1 bf16 (h3 then h4)
constexpr size_t OFF_LS   = OFF_H34 + (size_t)NN * C1 * 2;       // NN*2 f32
constexpr size_t OFF_LD   = OFF_LS  + (size_t)NN * 2 * 4;        // NN*2 f32
constexpr size_t OFF_DEG  = OFF_LD  + (size_t)NN * 2 * 4;        // NN i32
constexpr size_t OFF_OFFS = OFF_DEG + (size_t)NN * 4;            // NN+1 i32 (pad 80016)
constexpr size_t OFF_CUR  = OFF_OFFS + 80016;                    // NN i32
constexpr size_t OFF_CSRC = OFF_CUR + (size_t)NN * 4;            // EE i32
constexpr size_t OFF_GCNT = OFF_CSRC + (size_t)EE * 4;           // NG i32
constexpr size_t OFF_GOFF = OFF_GCNT + 512;                      // NG+1 i32 (pad 768)
constexpr size_t OFF_PART = OFF_GOFF + 768;                      // NBLK i32 (pad 512)
constexpr size_t OFF_PTOT = OFF_PART + 512;                      // 1 i32 (pad 256)
constexpr size_t OFF_Z1   = OFF_PTOT + 256;                      // NG*C1 bf16
constexpr size_t OFF_Z2   = OFF_Z1  + (size_t)NG * C1 * 2;
constexpr size_t OFF_ST   = OFF_Z2  + (size_t)NG * C1 * 2;       // S1,T1,S2,T2 (256 f32), S3,T3 (512 f32)
constexpr size_t OFF_W1T  = OFF_ST  + 8192;
constexpr size_t OFF_W2T  = OFF_W1T + (size_t)FD * C0 * 2;
constexpr size_t OFF_G0T  = OFF_W2T + (size_t)C0 * C0 * 2;
constexpr size_t OFF_G1T  = OFF_G0T + (size_t)C0 * C1 * 2;
constexpr size_t OFF_AUX  = OFF_G1T + (size_t)C1 * C1 * 2;
constexpr size_t OFF_FLAG = OFF_AUX  + 0;      // u32
constexpr size_t OFF_A0S  = OFF_AUX  + 256;    // 512 u16
constexpr size_t OFF_A0D  = OFF_AUX  + 1280;
constexpr size_t OFF_A1S  = OFF_AUX  + 2304;
constexpr size_t OFF_A1D  = OFF_AUX  + 3328;
constexpr size_t OFF_GB0  = OFF_AUX  + 4352;   // 512 f32
constexpr size_t OFF_GB1  = OFF_AUX  + 6400;
constexpr size_t OFF_FB1  = OFF_AUX  + 8448;   // 512 f32
constexpr size_t OFF_FB2  = OFF_AUX  + 10496;  // 10 f32 (pad 256)
constexpr size_t OFF_GMX  = OFF_AUX  + 10752;  // 2 f32
// end ~= 70 MB

// ---------------- helpers ----------------
__device__ inline float bf2f(u16 u) { return __uint_as_float(((unsigned)u) << 16); }
__device__ inline u16 f2bf(float f) {
    unsigned u = __float_as_uint(f);
    unsigned r = u + 0x7fffu + ((u >> 16) & 1u);   // RNE
    return (u16)(r >> 16);
}
// flag-driven load of an external float input (flag=1 -> f32, 0 -> bf16)
__device__ inline float ldf(const void* p, long i, unsigned f) {
    return f ? ((const float*)p)[i] : bf2f(((const u16*)p)[i]);
}
__device__ inline void unpack8(uint4 r, float* v) {
    v[0] = bf2f((u16)(r.x & 0xffff)); v[1] = bf2f((u16)(r.x >> 16));
    v[2] = bf2f((u16)(r.y & 0xffff)); v[3] = bf2f((u16)(r.y >> 16));
    v[4] = bf2f((u16)(r.z & 0xffff)); v[5] = bf2f((u16)(r.z >> 16));
    v[6] = bf2f((u16)(r.w & 0xffff)); v[7] = bf2f((u16)(r.w >> 16));
}

typedef __bf16 bf16x8_t __attribute__((ext_vector_type(8)));
typedef float  f32x4_t  __attribute__((ext_vector_type(4)));

// async 16B global -> LDS (wave-uniform LDS base + lane*16 layout)
__device__ __forceinline__ void gl_lds16(const u16* g, u16* l) {
    __builtin_amdgcn_global_load_lds((const __attribute__((address_space(1))) void*)g,
                                     (__attribute__((address_space(3))) void*)l, 16, 0, 0);
}

// ---------------- dtype detector ----------------
__global__ void detect_dtype(const u16* __restrict__ x, const u16* __restrict__ w,
                             const u16* __restrict__ fw, unsigned* flag) {
    __shared__ int cnt;
    if (threadIdx.x == 0) cnt = 0;
    __syncthreads();
    int c = 0;
    for (int i = threadIdx.x; i < 4096; i += 256) {
        c += (((x[i]  >> 7) & 0xFF) == 0xFF);
        c += (((w[i]  >> 7) & 0xFF) == 0xFF);
        c += (((fw[i] >> 7) & 0xFF) == 0xFF);
    }
    atomicAdd(&cnt, c);
    __syncthreads();
    if (threadIdx.x == 0) *flag = (cnt >= 2) ? 1u : 0u;  // 1 = f32 inputs
}

// ---------------- x -> internal bf16 copy (+ zero deg/gcnt) ----------------
__global__ void cvt_x(const unsigned* __restrict__ flag, const void* __restrict__ xin,
                      u16* __restrict__ XB, int* __restrict__ deg, int* __restrict__ gcnt) {
    int i = blockIdx.x * 256 + threadIdx.x;  // grid covers NN*FD/4 (2500 blocks >= NN/256)
    if (i < NN) deg[i] = 0;
    if (i < NG) gcnt[i] = 0;
    if (*flag) {
        float4 v = ((const float4*)xin)[i];
        ushort4 r;
        r.x = f2bf(v.x); r.y = f2bf(v.y); r.z = f2bf(v.z); r.w = f2bf(v.w);
        ((ushort4*)XB)[i] = r;
    } else {
        ((ushort4*)XB)[i] = ((const ushort4*)xin)[i];
    }
}

// ---------------- params prep ----------------
__global__ void prep_params(const unsigned* __restrict__ flag,
                            const void* g1, const void* b1, const void* m1, const void* v1, const void* lb1,
                            const void* g2, const void* b2, const void* m2, const void* v2, const void* lb2,
                            const void* g3, const void* b3, const void* m3, const void* v3,
                            const void* a0s, const void* a0d, const void* gb0in,
                            const void* a1s, const void* a1d, const void* gb1in,
                            const void* fb1in, const void* fb2in,
                            float* S1, float* T1, float* S2, float* T2, float* S3, float* T3,
                            u16* A0S, u16* A0D, u16* A1S, u16* A1D,
                            float* GB0, float* GB1, float* FB1, float* FB2) {
    unsigned f = *flag;
    int c = threadIdx.x;  // block 512
    if (c < 256) {
        float s = ldf(g1, c, f) / sqrtf(ldf(v1, c, f) + 1e-5f);
        S1[c] = s; T1[c] = s * (ldf(lb1, c, f) - ldf(m1, c, f)) + ldf(b1, c, f);
        float s2 = ldf(g2, c, f) / sqrtf(ldf(v2, c, f) + 1e-5f);
        S2[c] = s2; T2[c] = s2 * (ldf(lb2, c, f) - ldf(m2, c, f)) + ldf(b2, c, f);
    }
    float s3 = ldf(g3, c, f) / sqrtf(ldf(v3, c, f) + 1e-5f);
    S3[c] = s3; T3[c] = ldf(b3, c, f) - ldf(m3, c, f) * s3;
    A0S[c] = f2bf(ldf(a0s, c, f));
    A0D[c] = f2bf(ldf(a0d, c, f));
    A1S[c] = f2bf(ldf(a1s, c, f));
    A1D[c] = f2bf(ldf(a1d, c, f));
    GB0[c] = ldf(gb0in, c, f);
    GB1[c] = ldf(gb1in, c, f);
    FB1[c] = ldf(fb1in, c, f);
    if (c < NC) FB2[c] = ldf(fb2in, c, f);
}

// ---------------- all 4 weight transposes fused (B[K,N] -> BT[N,K] bf16) ----------------
__global__ void transpose_all(const unsigned* __restrict__ flag,
                              const void* __restrict__ w1, const void* __restrict__ w2,
                              const void* __restrict__ g0, const void* __restrict__ g1,
                              u16* __restrict__ w1T, u16* __restrict__ w2T,
                              u16* __restrict__ g0T, u16* __restrict__ g1T) {
    int b = blockIdx.x;
    const void* B; u16* BT; int K, logN, base;
    if (b < 128)      { B = w1; BT = w1T; K = FD; logN = 8; base = 0; }
    else if (b < 384) { B = w2; BT = w2T; K = C0; logN = 8; base = 128; }
    else if (b < 896) { B = g0; BT = g0T; K = C0; logN = 9; base = 384; }
    else              { B = g1; BT = g1T; K = C1; logN = 9; base = 896; }
    int idx = (b - base) * 256 + threadIdx.x;
    int N = 1 << logN;
    int k = idx >> logN, n = idx & (N - 1);
    u16 v = (*flag) ? f2bf(((const float*)B)[idx]) : ((const u16*)B)[idx];
    BT[(size_t)n * K + k] = v;
}

// ---------------- CSR build ----------------
__global__ void hist_k(const int* __restrict__ dst, const int* __restrict__ ew,
                       const int* __restrict__ batch, int* __restrict__ deg, int* __restrict__ gcnt) {
    int e = blockIdx.x * 256 + threadIdx.x;
    if (e < EE && ew[e] == 1) atomicAdd(&deg[dst[e]], 1);
    if (e < NN) atomicAdd(&gcnt[batch[e]], 1);
}
// hierarchical scan: (1) per-block local exclusive scan + block totals
__global__ __launch_bounds__(256) void scan_blk(const int* __restrict__ deg, int* __restrict__ off,
                                                int* __restrict__ part) {
    __shared__ int tmp[256];
    int tid = threadIdx.x, i = blockIdx.x * 256 + tid;
    int v = (i < NN) ? deg[i] : 0;
    tmp[tid] = v;
    __syncthreads();
#pragma unroll
    for (int s = 1; s < 256; s <<= 1) {
        int a = (tid >= s) ? tmp[tid - s] : 0;
        __syncthreads();
        if (tid >= s) tmp[tid] += a;
        __syncthreads();
    }
    if (i < NN) off[i] = tmp[tid] - v;   // block-local exclusive
    if (tid == 255) part[blockIdx.x] = tmp[255];
}
// (2) scan the NBLK partials + scan gcnt -> goff (one small block does both)
__global__ __launch_bounds__(128) void scan_small(int* __restrict__ part, int* __restrict__ ptot,
                                                  const int* __restrict__ gcnt, int* __restrict__ goff) {
    __shared__ int tmp[128];
    int tid = threadIdx.x;
    // partials scan
    int v = (tid < NBLK) ? part[tid] : 0;
    tmp[tid] = v;
    __syncthreads();
#pragma unroll
    for (int s = 1; s < 128; s <<= 1) {
        int a = (tid >= s) ? tmp[tid - s] : 0;
        __syncthreads();
        if (tid >= s) tmp[tid] += a;
        __syncthreads();
    }
    if (tid < NBLK) part[tid] = tmp[tid] - v;  // exclusive
    if (tid == 127) *ptot = tmp[127];
    __syncthreads();
    // graph-count scan
    int g = gcnt[tid];
    tmp[tid] = g;
    __syncthreads();
#pragma unroll
    for (int s = 1; s < 128; s <<= 1) {
        int a = (tid >= s) ? tmp[tid - s] : 0;
        __syncthreads();
        if (tid >= s) tmp[tid] += a;
        __syncthreads();
    }
    goff[tid] = tmp[tid] - g;
    if (tid == 127) goff[128] = tmp[127];
}
// (3) add block prefix, emit cursor copy and total
__global__ __launch_bounds__(256) void scan_add(int* __restrict__ off, const int* __restrict__ part,
                                                const int* __restrict__ ptot, int* __restrict__ cursor) {
    int tid = threadIdx.x, i = blockIdx.x * 256 + tid;
    if (i < NN) {
        int o = off[i] + part[blockIdx.x];
        off[i] = o;
        cursor[i] = o;
    }
    if (i == 0) off[NN] = *ptot;
}
__global__ void csr_fill(const int* __restrict__ src, const int* __restrict__ dst, const int* __restrict__ ew,
                         int* __restrict__ cursor, int* __restrict__ csrc) {
    int e = blockIdx.x * 256 + threadIdx.x;
    if (e >= EE) return;
    if (ew[e] != 1) return;
    int p = atomicAdd(&cursor[dst[e]], 1);
    csrc[p] = src[e];
}

// ---------------- MFMA GEMM (m97-style LDS-staged): C[M,N] = A[M,K] @ B[K,N] ----------------
// 128x128 block, 4 waves 2x2 (64x64 per wave), BK=32, async global->LDS staging.
// EPI: 0 = store raw bf16, 1 = relu(acc*S[col] + T[col])
template <int EPI>
__global__ __launch_bounds__(256) void gemm_tile(const u16* __restrict__ A, const u16* __restrict__ BT,
                                                 u16* __restrict__ Cm,
                                                 const float* __restrict__ S, const float* __restrict__ T,
                                                 int M, int N, int K) {
    __shared__ u16 As[128 * 32];   // [row][k] row-major, unpadded (global_load_lds layout)
    __shared__ u16 Bs[128 * 32];   // [col][k]
    const int tid  = threadIdx.x;
    const int wave = tid >> 6;
    const int lane = tid & 63;
    const int quad = lane >> 4;
    const int l16  = lane & 15;
    const int wr0  = (wave >> 1) * 64;
    const int wc0  = (wave & 1) * 64;
    const int row0 = blockIdx.x * 128;
    const int col0 = blockIdx.y * 128;

    const int lr = lane >> 2;          // 0..15 row within 16-row segment
    const int lk = (lane & 3) * 8;     // 0,8,16,24 element offset in k
    int r0l = wave * 32 + lr;
    int r1l = r0l + 16;
    int gr0 = row0 + r0l; if (gr0 >= M) gr0 = M - 1;   // clamp: loads valid, stores guarded
    int gr1 = row0 + r1l; if (gr1 >= M) gr1 = M - 1;
    const u16* ga0 = A  + (size_t)gr0 * K + lk;
    const u16* ga1 = A  + (size_t)gr1 * K + lk;
    const u16* gb0 = BT + (size_t)(col0 + r0l) * K + lk;
    const u16* gb1 = BT + (size_t)(col0 + r1l) * K + lk;
    u16* la0 = As + (size_t)(wave * 32)      * 32 + lane * 8;
    u16* la1 = As + (size_t)(wave * 32 + 16) * 32 + lane * 8;
    u16* lb0 = Bs + (size_t)(wave * 32)      * 32 + lane * 8;
    u16* lb1 = Bs + (size_t)(wave * 32 + 16) * 32 + lane * 8;

    f32x4_t acc[4][4];
#pragma unroll
    for (int r = 0; r < 4; r++)
#pragma unroll
        for (int c = 0; c < 4; c++)
#pragma unroll
            for (int i = 0; i < 4; i++) acc[r][c][i] = 0.f;

    for (int k0 = 0; k0 < K; k0 += 32) {
        gl_lds16(ga0 + k0, la0);
        gl_lds16(ga1 + k0, la1);
        gl_lds16(gb0 + k0, lb0);
        gl_lds16(gb1 + k0, lb1);
        __syncthreads();   // drains vmcnt (async LDS writes) + all waves

        bf16x8_t a[4], b[4];
#pragma unroll
        for (int r = 0; r < 4; r++)
            a[r] = *(const bf16x8_t*)(As + (size_t)(wr0 + r * 16 + l16) * 32 + quad * 8);
#pragma unroll
        for (int c = 0; c < 4; c++)
            b[c] = *(const bf16x8_t*)(Bs + (size_t)(wc0 + c * 16 + l16) * 32 + quad * 8);
#pragma unroll
        for (int r = 0; r < 4; r++)
#pragma unroll
            for (int c = 0; c < 4; c++)
                acc[r][c] = __builtin_amdgcn_mfma_f32_16x16x32_bf16(a[r], b[c], acc[r][c], 0, 0, 0);
        __syncthreads();   // LDS reads done before next staging overwrites
    }

#pragma unroll
    for (int r = 0; r < 4; r++) {
        int rb = row0 + wr0 + r * 16 + quad * 4;
#pragma unroll
        for (int c = 0; c < 4; c++) {
            int col = col0 + wc0 + c * 16 + l16;
            float sc = (EPI == 1) ? S[col] : 0.f;
            float sh = (EPI == 1) ? T[col] : 0.f;
#pragma unroll
            for (int i = 0; i < 4; i++) {
                int row = rb + i;
                if (row < M) {
                    float v = acc[r][c][i];
                    if (EPI == 1) v = fmaxf(v * sc + sh, 0.f);
                    Cm[(size_t)row * N + col] = f2bf(v);
                }
            }
        }
    }
}

// ---------------- GAT: per-node attention logits ----------------
__global__ __launch_bounds__(256) void gat_logits(const u16* __restrict__ xw, const u16* __restrict__ asrc,
                                                  const u16* __restrict__ adst, float* __restrict__ ls,
                                                  float* __restrict__ ld) {
    int n = blockIdx.x * 4 + (threadIdx.x >> 6);
    if (n >= NN) return;
    int lane = threadIdx.x & 63;
    uint4 xv = ((const uint4*)(xw + (size_t)n * C1))[lane];
    uint4 sv = ((const uint4*)asrc)[lane];
    uint4 dv = ((const uint4*)adst)[lane];
    float x[8], a[8], d[8];
    unpack8(xv, x); unpack8(sv, a); unpack8(dv, d);
    float ps = 0.f, pd = 0.f;
#pragma unroll
    for (int j = 0; j < 8; j++) { ps += x[j] * a[j]; pd += x[j] * d[j]; }
#pragma unroll
    for (int m = 16; m >= 1; m >>= 1) { ps += __shfl_xor(ps, m); pd += __shfl_xor(pd, m); }
    if ((lane & 31) == 0) {
        int h = lane >> 5;
        ls[n * 2 + h] = ps;
        ld[n * 2 + h] = pd;
    }
}

// ---------------- global max of ls per head (single block) ----------------
__global__ __launch_bounds__(1024) void ls_max(const float* __restrict__ ls, float* __restrict__ gmx) {
    __shared__ float s0[16], s1[16];
    int t = threadIdx.x;
    float m0 = -1e30f, m1 = -1e30f;
    for (int n = t; n < NN; n += 1024) {
        float2 v = ((const float2*)ls)[n];
        m0 = fmaxf(m0, v.x); m1 = fmaxf(m1, v.y);
    }
#pragma unroll
    for (int o = 32; o >= 1; o >>= 1) {
        m0 = fmaxf(m0, __shfl_xor(m0, o));
        m1 = fmaxf(m1, __shfl_xor(m1, o));
    }
    if ((t & 63) == 0) { s0[t >> 6] = m0; s1[t >> 6] = m1; }
    __syncthreads();
    if (t == 0) {
        float a = -1e30f, b = -1e30f;
#pragma unroll
        for (int i = 0; i < 16; i++) { a = fmaxf(a, s0[i]); b = fmaxf(b, s1[i]); }
        gmx[0] = a; gmx[1] = b;
    }
}

// ---------------- fused GAT aggregation: single-sweep online softmax + gather ----------------
// one wave per node; lanes 0..31 head 0, 32..63 head 1; lane covers features [lane*8, lane*8+8)
// p = exp(v - mhat) with mhat = leaky(gmax + ld) an upper bound => p <= 1, no overflow;
// alpha = p / sum(p) is shift-invariant so result matches the reference exactly.
__global__ __launch_bounds__(256) void gat_aggregate(const int* __restrict__ off, const int* __restrict__ csrc,
                                                     const float* __restrict__ ls, const float* __restrict__ ld,
                                                     const float* __restrict__ gmx, const u16* __restrict__ xw,
                                                     const float* __restrict__ bias, u16* __restrict__ outh) {
    int n = blockIdx.x * 4 + (threadIdx.x >> 6);
    if (n >= NN) return;
    int lane = threadIdx.x & 63;
    int h = lane >> 5;
    int beg = off[n], end = off[n + 1];
    float ldh = ld[n * 2 + h];
    float gm = gmx[h] + ldh;
    float mhat = gm > 0.f ? gm : 0.2f * gm;   // leaky is monotone -> valid upper bound

    float acc[8];
#pragma unroll
    for (int j = 0; j < 8; j++) acc[j] = 0.f;
    float den = 0.f;

    float lsv = 0.f; uint4 row;
    if (beg < end) {
        int s0 = csrc[beg];
        lsv = ls[s0 * 2 + h];
        row = ((const uint4*)(xw + (size_t)s0 * C1))[lane];
    }
    for (int i = beg; i < end; i++) {
        float cls = lsv;
        uint4 crow = row;
        if (i + 1 < end) {                       // prefetch next edge (1-deep pipeline)
            int s2 = csrc[i + 1];
            lsv = ls[s2 * 2 + h];
            row = ((const uint4*)(xw + (size_t)s2 * C1))[lane];
        }
        float v = cls + ldh;
        v = v > 0.f ? v : 0.2f * v;
        float p = __expf(v - mhat);
        den += p;
        float x[8];
        unpack8(crow, x);
#pragma unroll
        for (int j = 0; j < 8; j++) acc[j] = fmaf(p, x[j], acc[j]);
    }

    float inv = 1.f / fmaxf(den, 1e-30f);
    ushort4 r0, r1;
    int cb = lane * 8;
    float o0 = acc[0] * inv + bias[cb + 0], o1 = acc[1] * inv + bias[cb + 1];
    float o2 = acc[2] * inv + bias[cb + 2], o3 = acc[3] * inv + bias[cb + 3];
    float o4 = acc[4] * inv + bias[cb + 4], o5 = acc[5] * inv + bias[cb + 5];
    float o6 = acc[6] * inv + bias[cb + 6], o7 = acc[7] * inv + bias[cb + 7];
    r0.x = f2bf(o0); r0.y = f2bf(o1); r0.z = f2bf(o2); r0.w = f2bf(o3);
    r1.x = f2bf(o4); r1.y = f2bf(o5); r1.z = f2bf(o6); r1.w = f2bf(o7);
    ushort4* dst4 = (ushort4*)(outh + (size_t)n * C1 + cb);
    dst4[0] = r0; dst4[1] = r1;
}

// ---------------- fused pool + BN3 + ReLU (block per graph; batch is sorted) ----------------
__global__ __launch_bounds__(512) void pool_bn(const u16* __restrict__ h4, const int* __restrict__ goff,
                                               const float* __restrict__ S3, const float* __restrict__ T3,
                                               u16* __restrict__ z1) {
    int g = blockIdx.x, t = threadIdx.x;
    int b = goff[g], e = goff[g + 1];
    float s = 0.f;
    for (int n = b; n < e; n++) s += bf2f(h4[(size_t)n * C1 + t]);
    float mean = s / fmaxf((float)(e - b), 1.f);
    float v = mean * S3[t] + T3[t];
    z1[(size_t)g * C1 + t] = f2bf(fmaxf(v, 0.f));
}

// ---------------- head ----------------
__global__ __launch_bounds__(512) void head_fc1(const unsigned* __restrict__ flag, const u16* __restrict__ z1,
                                                const void* __restrict__ w1, const float* __restrict__ FB1,
                                                u16* __restrict__ z2) {
    __shared__ float zrow[512];
    int g = blockIdx.x, t = threadIdx.x;
    zrow[t] = bf2f(z1[(size_t)g * 512 + t]);
    __syncthreads();
    float acc = 0.f;
    if (*flag) {
        const float* w = (const float*)w1;
        for (int k = 0; k < 512; k++) acc = fmaf(zrow[k], w[(size_t)k * 512 + t], acc);
    } else {
        const u16* w = (const u16*)w1;
        for (int k = 0; k < 512; k++) acc = fmaf(zrow[k], bf2f(w[(size_t)k * 512 + t]), acc);
    }
    acc += FB1[t];
    z2[(size_t)g * 512 + t] = f2bf(fmaxf(acc, 0.f));
}
__global__ __launch_bounds__(64) void head_fc2(const unsigned* __restrict__ flag, const u16* __restrict__ z2,
                                               const void* __restrict__ w2, const float* __restrict__ FB2,
                                               void* __restrict__ out) {
    int g = blockIdx.x, o = blockIdx.y, lane = threadIdx.x;
    unsigned f = *flag;
    float acc = 0.f;
    if (f) {
        const float* w = (const float*)w2;
        for (int k = lane; k < 512; k += 64) acc += bf2f(z2[(size_t)g * 512 + k]) * w[(size_t)k * NC + o];
    } else {
        const u16* w = (const u16*)w2;
        for (int k = lane; k < 512; k += 64) acc += bf2f(z2[(size_t)g * 512 + k]) * bf2f(w[(size_t)k * NC + o]);
    }
#pragma unroll
    for (int m = 32; m >= 1; m >>= 1) acc += __shfl_xor(acc, m);
    if (lane == 0) {
        float v = acc + FB2[o];
        if (f) ((float*)out)[g * NC + o] = v;
        else   ((u16*)out)[g * NC + o] = f2bf(v);
    }
}

// ---------------- launch ----------------
extern "C" void kernel_launch(void* const* d_in, const int* in_sizes, int n_in,
                              void* d_out, int out_size, void* d_ws, size_t ws_size,
                              hipStream_t stream) {
    (void)in_sizes; (void)n_in; (void)out_size; (void)ws_size;

    const void* x      = d_in[0];
    const int* ei      = (const int*)d_in[1];
    const int* src     = ei;
    const int* dst     = ei + EE;
    const int* ew      = (const int*)d_in[2];
    const int* batch   = (const int*)d_in[3];
    const void* mlp_w1 = d_in[4];
    const void* mlp_b1 = d_in[5];
    const void *bn1g = d_in[6], *bn1b = d_in[7], *bn1m = d_in[8], *bn1v = d_in[9];
    const void* mlp_w2 = d_in[10];
    const void* mlp_b2 = d_in[11];
    const void *bn2g = d_in[12], *bn2b = d_in[13], *bn2m = d_in[14], *bn2v = d_in[15];
    const void* g0w    = d_in[16];
    const void* g0as   = d_in[17];
    const void* g0ad   = d_in[18];
    const void* g0bias = d_in[19];
    const void* g1w    = d_in[20];
    const void* g1as   = d_in[21];
    const void* g1ad   = d_in[22];
    const void* g1bias = d_in[23];
    const void *bn3g = d_in[24], *bn3b = d_in[25], *bn3m = d_in[26], *bn3v = d_in[27];
    const void* fin_w1 = d_in[28];
    const void* fin_b1 = d_in[29];
    const void* fin_w2 = d_in[30];
    const void* fin_b2 = d_in[31];

    char* ws = (char*)d_ws;
    u16*  XB   = (u16*)(ws + OFF_XB);
    u16*  h1   = (u16*)(ws + OFF_H1);
    u16*  h2   = (u16*)(ws + OFF_H2);
    u16*  xw   = (u16*)(ws + OFF_XW);
    u16*  h34  = (u16*)(ws + OFF_H34);
    float* ls  = (float*)(ws + OFF_LS);
    float* ld  = (float*)(ws + OFF_LD);
    int*  deg  = (int*)(ws + OFF_DEG);
    int*  off  = (int*)(ws + OFF_OFFS);
    int*  cur  = (int*)(ws + OFF_CUR);
    int*  csrc = (int*)(ws + OFF_CSRC);
    int*  gcnt = (int*)(ws + OFF_GCNT);
    int*  goff = (int*)(ws + OFF_GOFF);
    int*  part = (int*)(ws + OFF_PART);
    int*  ptot = (int*)(ws + OFF_PTOT);
    u16*  z1   = (u16*)(ws + OFF_Z1);
    u16*  z2   = (u16*)(ws + OFF_Z2);
    float* S1 = (float*)(ws + OFF_ST);
    float* T1 = S1 + 256;
    float* S2 = T1 + 256;
    float* T2 = S2 + 256;
    float* S3 = T2 + 256;
    float* T3 = S3 + 512;
    u16* w1T = (u16*)(ws + OFF_W1T);
    u16* w2T = (u16*)(ws + OFF_W2T);
    u16* g0T = (u16*)(ws + OFF_G0T);
    u16* g1T = (u16*)(ws + OFF_G1T);
    unsigned* flag = (unsigned*)(ws + OFF_FLAG);
    u16* A0S = (u16*)(ws + OFF_A0S);
    u16* A0D = (u16*)(ws + OFF_A0D);
    u16* A1S = (u16*)(ws + OFF_A1S);
    u16* A1D = (u16*)(ws + OFF_A1D);
    float* GB0 = (float*)(ws + OFF_GB0);
    float* GB1 = (float*)(ws + OFF_GB1);
    float* FB1 = (float*)(ws + OFF_FB1);
    float* FB2 = (float*)(ws + OFF_FB2);
    float* GMX = (float*)(ws + OFF_GMX);

    // dtype detection + input normalization (+ deg/gcnt zero)
    detect_dtype<<<1, 256, 0, stream>>>((const u16*)x, (const u16*)mlp_w1, (const u16*)fin_w1, flag);
    cvt_x<<<(NN * FD / 4) / 256, 256, 0, stream>>>(flag, x, XB, deg, gcnt);
    prep_params<<<1, 512, 0, stream>>>(flag,
                                       bn1g, bn1b, bn1m, bn1v, mlp_b1,
                                       bn2g, bn2b, bn2m, bn2v, mlp_b2,
                                       bn3g, bn3b, bn3m, bn3v,
                                       g0as, g0ad, g0bias, g1as, g1ad, g1bias,
                                       fin_b1, fin_b2,
                                       S1, T1, S2, T2, S3, T3,
                                       A0S, A0D, A1S, A1D, GB0, GB1, FB1, FB2);
    transpose_all<<<1920, 256, 0, stream>>>(flag, mlp_w1, mlp_w2, g0w, g1w, w1T, w2T, g0T, g1T);

    // CSR build (graph fixed across both layers) + graph offsets
    hist_k<<<EE / 256, 256, 0, stream>>>(dst, ew, batch, deg, gcnt);
    scan_blk<<<NBLK, 256, 0, stream>>>(deg, off, part);
    scan_small<<<1, 128, 0, stream>>>(part, ptot, gcnt, goff);
    scan_add<<<NBLK, 256, 0, stream>>>(off, part, ptot, cur);
    csr_fill<<<EE / 256, 256, 0, stream>>>(src, dst, ew, cur, csrc);

    // MLP (157 row-blocks of 128 cover 20096 >= 20000)
    gemm_tile<1><<<dim3(157, 2), 256, 0, stream>>>(XB, w1T, h1, S1, T1, NN, C0, FD);
    gemm_tile<1><<<dim3(157, 2), 256, 0, stream>>>(h1, w2T, h2, S2, T2, NN, C0, C0);

    // GAT layer 0
    gemm_tile<0><<<dim3(157, 4), 256, 0, stream>>>(h2, g0T, xw, nullptr, nullptr, NN, C1, C0);
    gat_logits<<<NN / 4, 256, 0, stream>>>(xw, A0S, A0D, ls, ld);
    ls_max<<<1, 1024, 0, stream>>>(ls, GMX);
    gat_aggregate<<<NN / 4, 256, 0, stream>>>(off, csrc, ls, ld, GMX, xw, GB0, h34);

    // GAT layer 1
    gemm_tile<0><<<dim3(157, 4), 256, 0, stream>>>(h34, g1T, xw, nullptr, nullptr, NN, C1, C1);
    gat_logits<<<NN / 4, 256, 0, stream>>>(xw, A1S, A1D, ls, ld);
    ls_max<<<1, 1024, 0, stream>>>(ls, GMX);
    gat_aggregate<<<NN / 4, 256, 0, stream>>>(off, csrc, ls, ld, GMX, xw, GB1, h34);  // h4

    // pool + head
    pool_bn<<<NG, 512, 0, stream>>>(h34, goff, S3, T3, z1);
    head_fc1<<<NG, 512, 0, stream>>>(flag, z1, fin_w1, FB1, z2);
    head_fc2<<<dim3(NG, NC), 64, 0, stream>>>(flag, z2, fin_w2, FB2, d_out);
}

// Round 7
// 433.895 us; speedup vs baseline: 21.9204x; 1.1084x over previous
//
#include <hip/hip_runtime.h>

typedef unsigned short u16;

// ---------------- problem constants ----------------
constexpr int NN = 20000;   // nodes
constexpr int EE = 320000;  // edges
constexpr int FD = 128;     // input features
constexpr int C0 = 256;     // hidden (mlp)
constexpr int C1 = 512;     // H*C for GAT
constexpr int NG = 128;     // graphs
constexpr int NC = 10;      // classes
constexpr int NBLK = (NN + 255) / 256;  // 79
constexpr int HB  = 320;                // hist/fill blocks
constexpr int EST = HB * 256;           // edge stride (81920); 4 chunks cover EE

// ---------------- workspace layout (bytes) ----------------
constexpr size_t OFF_XB   = 0;                                   // NN*FD bf16
constexpr size_t OFF_H1   = OFF_XB  + (size_t)NN * FD * 2;       // NN*C0 bf16
constexpr size_t OFF_H2   = OFF_H1  + (size_t)NN * C0 * 2;       // NN*C0 bf16
constexpr size_t OFF_XW   = OFF_H2  + (size_t)NN * C0 * 2;       // NN*C1 bf16
constexpr size_t OFF_H34  = OFF_XW  + (size_t)NN * C1 * 2;       // NN*C1 bf16 (h3 then h4)
constexpr size_t OFF_LS   = OFF_H34 + (size_t)NN * C1 * 2;       // NN*2 f32
constexpr size_t OFF_LD   = OFF_LS  + (size_t)NN * 2 * 4;        // NN*2 f32
constexpr size_t OFF_DEG  = OFF_LD  + (size_t)NN * 2 * 4;        // NN i32
constexpr size_t OFF_OFFS = OFF_DEG + (size_t)NN * 4;            // NN+1 i32 (pad 80016)
constexpr size_t OFF_CUR  = OFF_OFFS + 80016;                    // NN i32
constexpr size_t OFF_CSRC = OFF_CUR + (size_t)NN * 4;            // EE i32
constexpr size_t OFF_GCNT = OFF_CSRC + (size_t)EE * 4;           // NG i32
constexpr size_t OFF_GOFF = OFF_GCNT + 512;                      // NG+1 i32 (pad 768)
constexpr size_t OFF_PART = OFF_GOFF + 768;                      // NBLK i32 (pad 512)
constexpr size_t OFF_PTOT = OFF_PART + 512;                      // 1 i32 (pad 256)
constexpr size_t OFF_Z1   = OFF_PTOT + 256;                      // NG*C1 bf16
constexpr size_t OFF_Z2   = OFF_Z1  + (size_t)NG * C1 * 2;
constexpr size_t OFF_ST   = OFF_Z2  + (size_t)NG * C1 * 2;       // S1,T1,S2,T2 (256 f32), S3,T3 (512 f32)
constexpr size_t OFF_W1T  = OFF_ST  + 8192;
constexpr size_t OFF_W2T  = OFF_W1T + (size_t)FD * C0 * 2;
constexpr size_t OFF_G0T  = OFF_W2T + (size_t)C0 * C0 * 2;
constexpr size_t OFF_G1T  = OFF_G0T + (size_t)C0 * C1 * 2;
constexpr size_t OFF_AUX  = OFF_G1T + (size_t)C1 * C1 * 2;
constexpr size_t OFF_FLAG = OFF_AUX  + 0;      // u32
constexpr size_t OFF_A0S  = OFF_AUX  + 256;    // 512 u16
constexpr size_t OFF_A0D  = OFF_AUX  + 1280;
constexpr size_t OFF_A1S  = OFF_AUX  + 2304;
constexpr size_t OFF_A1D  = OFF_AUX  + 3328;
constexpr size_t OFF_GB0  = OFF_AUX  + 4352;   // 512 f32
constexpr size_t OFF_GB1  = OFF_AUX  + 6400;
constexpr size_t OFF_FB1  = OFF_AUX  + 8448;   // 512 f32
constexpr size_t OFF_FB2  = OFF_AUX  + 10496;  // 10 f32 (pad 256)
constexpr size_t OFF_GMX  = OFF_AUX  + 10752;  // 4 u32 (encoded max: layer0 h0,h1; layer1 h0,h1)
// end ~= 70 MB

// ---------------- helpers ----------------
__device__ inline float bf2f(u16 u) { return __uint_as_float(((unsigned)u) << 16); }
__device__ inline u16 f2bf(float f) {
    unsigned u = __float_as_uint(f);
    unsigned r = u + 0x7fffu + ((u >> 16) & 1u);   // RNE
    return (u16)(r >> 16);
}
// flag-driven load of an external float input (flag=1 -> f32, 0 -> bf16)
__device__ inline float ldf(const void* p, long i, unsigned f) {
    return f ? ((const float*)p)[i] : bf2f(((const u16*)p)[i]);
}
__device__ inline unsigned encf(float f) {  // monotonic float->uint for atomicMax
    unsigned u = __float_as_uint(f);
    return (u & 0x80000000u) ? ~u : (u | 0x80000000u);
}
__device__ inline float decf(unsigned e) {
    return (e & 0x80000000u) ? __uint_as_float(e ^ 0x80000000u) : __uint_as_float(~e);
}
__device__ inline void unpack8(uint4 r, float* v) {
    v[0] = bf2f((u16)(r.x & 0xffff)); v[1] = bf2f((u16)(r.x >> 16));
    v[2] = bf2f((u16)(r.y & 0xffff)); v[3] = bf2f((u16)(r.y >> 16));
    v[4] = bf2f((u16)(r.z & 0xffff)); v[5] = bf2f((u16)(r.z >> 16));
    v[6] = bf2f((u16)(r.w & 0xffff)); v[7] = bf2f((u16)(r.w >> 16));
}

typedef __bf16 bf16x8_t __attribute__((ext_vector_type(8)));
typedef float  f32x4_t  __attribute__((ext_vector_type(4)));

// async 16B global -> LDS (wave-uniform LDS base + lane*16 layout)
__device__ __forceinline__ void gl_lds16(const u16* g, u16* l) {
    __builtin_amdgcn_global_load_lds((const __attribute__((address_space(1))) void*)g,
                                     (__attribute__((address_space(3))) void*)l, 16, 0, 0);
}

// ---------------- dtype detector ----------------
__global__ void detect_dtype(const u16* __restrict__ x, const u16* __restrict__ w,
                             const u16* __restrict__ fw, unsigned* flag) {
    __shared__ int cnt;
    if (threadIdx.x == 0) cnt = 0;
    __syncthreads();
    int c = 0;
    for (int i = threadIdx.x; i < 4096; i += 256) {
        c += (((x[i]  >> 7) & 0xFF) == 0xFF);
        c += (((w[i]  >> 7) & 0xFF) == 0xFF);
        c += (((fw[i] >> 7) & 0xFF) == 0xFF);
    }
    atomicAdd(&cnt, c);
    __syncthreads();
    if (threadIdx.x == 0) *flag = (cnt >= 2) ? 1u : 0u;  // 1 = f32 inputs
}

// ---------------- x -> internal bf16 copy (+ zero deg/gcnt, init gmx) ----------------
__global__ void cvt_x(const unsigned* __restrict__ flag, const void* __restrict__ xin,
                      u16* __restrict__ XB, int* __restrict__ deg, int* __restrict__ gcnt,
                      unsigned* __restrict__ gmxu) {
    int i = blockIdx.x * 256 + threadIdx.x;  // grid covers NN*FD/4 (2500 blocks)
    if (i < NN) deg[i] = 0;
    if (i < NG) gcnt[i] = 0;
    if (i < 4)  gmxu[i] = encf(-1e30f);
    if (*flag) {
        float4 v = ((const float4*)xin)[i];
        ushort4 r;
        r.x = f2bf(v.x); r.y = f2bf(v.y); r.z = f2bf(v.z); r.w = f2bf(v.w);
        ((ushort4*)XB)[i] = r;
    } else {
        ((ushort4*)XB)[i] = ((const ushort4*)xin)[i];
    }
}

// ---------------- params prep ----------------
__global__ void prep_params(const unsigned* __restrict__ flag,
                            const void* g1, const void* b1, const void* m1, const void* v1, const void* lb1,
                            const void* g2, const void* b2, const void* m2, const void* v2, const void* lb2,
                            const void* g3, const void* b3, const void* m3, const void* v3,
                            const void* a0s, const void* a0d, const void* gb0in,
                            const void* a1s, const void* a1d, const void* gb1in,
                            const void* fb1in, const void* fb2in,
                            float* S1, float* T1, float* S2, float* T2, float* S3, float* T3,
                            u16* A0S, u16* A0D, u16* A1S, u16* A1D,
                            float* GB0, float* GB1, float* FB1, float* FB2) {
    unsigned f = *flag;
    int c = threadIdx.x;  // block 512
    if (c < 256) {
        float s = ldf(g1, c, f) / sqrtf(ldf(v1, c, f) + 1e-5f);
        S1[c] = s; T1[c] = s * (ldf(lb1, c, f) - ldf(m1, c, f)) + ldf(b1, c, f);
        float s2 = ldf(g2, c, f) / sqrtf(ldf(v2, c, f) + 1e-5f);
        S2[c] = s2; T2[c] = s2 * (ldf(lb2, c, f) - ldf(m2, c, f)) + ldf(b2, c, f);
    }
    float s3 = ldf(g3, c, f) / sqrtf(ldf(v3, c, f) + 1e-5f);
    S3[c] = s3; T3[c] = ldf(b3, c, f) - ldf(m3, c, f) * s3;
    A0S[c] = f2bf(ldf(a0s, c, f));
    A0D[c] = f2bf(ldf(a0d, c, f));
    A1S[c] = f2bf(ldf(a1s, c, f));
    A1D[c] = f2bf(ldf(a1d, c, f));
    GB0[c] = ldf(gb0in, c, f);
    GB1[c] = ldf(gb1in, c, f);
    FB1[c] = ldf(fb1in, c, f);
    if (c < NC) FB2[c] = ldf(fb2in, c, f);
}

// ---------------- all 4 weight transposes fused (B[K,N] -> BT[N,K] bf16) ----------------
__global__ void transpose_all(const unsigned* __restrict__ flag,
                              const void* __restrict__ w1, const void* __restrict__ w2,
                              const void* __restrict__ g0, const void* __restrict__ g1,
                              u16* __restrict__ w1T, u16* __restrict__ w2T,
                              u16* __restrict__ g0T, u16* __restrict__ g1T) {
    int b = blockIdx.x;
    const void* B; u16* BT; int K, logN, base;
    if (b < 128)      { B = w1; BT = w1T; K = FD; logN = 8; base = 0; }
    else if (b < 384) { B = w2; BT = w2T; K = C0; logN = 8; base = 128; }
    else if (b < 896) { B = g0; BT = g0T; K = C0; logN = 9; base = 384; }
    else              { B = g1; BT = g1T; K = C1; logN = 9; base = 896; }
    int idx = (b - base) * 256 + threadIdx.x;
    int N = 1 << logN;
    int k = idx >> logN, n = idx & (N - 1);
    u16 v = (*flag) ? f2bf(((const float*)B)[idx]) : ((const u16*)B)[idx];
    BT[(size_t)n * K + k] = v;
}

// ---------------- CSR build: histograms (pipelined atomics + wave-run gcnt) ----------------
__global__ __launch_bounds__(256) void hist_k(const int* __restrict__ dst, const int* __restrict__ ew,
                                              const int* __restrict__ batch,
                                              int* __restrict__ deg, int* __restrict__ gcnt) {
    int tid = blockIdx.x * 256 + threadIdx.x;
    int lane = threadIdx.x & 63;
    // edges: 4 independent atomic chains per thread (outstanding-transaction pipelining)
#pragma unroll
    for (int j = 0; j < 4; j++) {
        int e = tid + j * EST;
        if (e < EE && ew[e] == 1) atomicAdd(&deg[dst[e]], 1);
    }
    // nodes: batch is sorted -> one atomic per run per wave (kills same-address serialization)
    int n = tid;
    if (n < NN) {
        int g = batch[n];
        int pg = __shfl_up(g, 1);
        bool head = (lane == 0) || (pg != g);
        unsigned long long act = __ballot(1);
        unsigned long long hm  = __ballot(head);
        if (head) {
            unsigned long long above = (lane < 63) ? ((hm >> (lane + 1)) << (lane + 1)) : 0ull;
            int limit = 64 - __builtin_clzll(act);           // highest active lane + 1
            int nxt = above ? __builtin_ctzll(above) : limit;
            atomicAdd(&gcnt[g], nxt - lane);
        }
    }
}
// hierarchical scan: (1) per-block local exclusive scan + block totals
__global__ __launch_bounds__(256) void scan_blk(const int* __restrict__ deg, int* __restrict__ off,
                                                int* __restrict__ part) {
    __shared__ int tmp[256];
    int tid = threadIdx.x, i = blockIdx.x * 256 + tid;
    int v = (i < NN) ? deg[i] : 0;
    tmp[tid] = v;
    __syncthreads();
#pragma unroll
    for (int s = 1; s < 256; s <<= 1) {
        int a = (tid >= s) ? tmp[tid - s] : 0;
        __syncthreads();
        if (tid >= s) tmp[tid] += a;
        __syncthreads();
    }
    if (i < NN) off[i] = tmp[tid] - v;   // block-local exclusive
    if (tid == 255) part[blockIdx.x] = tmp[255];
}
// (2) scan the NBLK partials + scan gcnt -> goff (one small block does both)
__global__ __launch_bounds__(128) void scan_small(int* __restrict__ part, int* __restrict__ ptot,
                                                  const int* __restrict__ gcnt, int* __restrict__ goff) {
    __shared__ int tmp[128];
    int tid = threadIdx.x;
    int v = (tid < NBLK) ? part[tid] : 0;
    tmp[tid] = v;
    __syncthreads();
#pragma unroll
    for (int s = 1; s < 128; s <<= 1) {
        int a = (tid >= s) ? tmp[tid - s] : 0;
        __syncthreads();
        if (tid >= s) tmp[tid] += a;
        __syncthreads();
    }
    if (tid < NBLK) part[tid] = tmp[tid] - v;  // exclusive
    if (tid == 127) *ptot = tmp[127];
    __syncthreads();
    int g = gcnt[tid];
    tmp[tid] = g;
    __syncthreads();
#pragma unroll
    for (int s = 1; s < 128; s <<= 1) {
        int a = (tid >= s) ? tmp[tid - s] : 0;
        __syncthreads();
        if (tid >= s) tmp[tid] += a;
        __syncthreads();
    }
    goff[tid] = tmp[tid] - g;
    if (tid == 127) goff[128] = tmp[127];
}
// (3) add block prefix, emit cursor copy and total
__global__ __launch_bounds__(256) void scan_add(int* __restrict__ off, const int* __restrict__ part,
                                                const int* __restrict__ ptot, int* __restrict__ cursor) {
    int tid = threadIdx.x, i = blockIdx.x * 256 + tid;
    if (i < NN) {
        int o = off[i] + part[blockIdx.x];
        off[i] = o;
        cursor[i] = o;
    }
    if (i == 0) off[NN] = *ptot;
}
// fill: 4 independent atomic-return chains per thread
__global__ __launch_bounds__(256) void csr_fill(const int* __restrict__ src, const int* __restrict__ dst,
                                                const int* __restrict__ ew,
                                                int* __restrict__ cursor, int* __restrict__ csrc) {
    int tid = blockIdx.x * 256 + threadIdx.x;
    bool ok[4]; int sv[4]; int p[4];
#pragma unroll
    for (int j = 0; j < 4; j++) {
        int e = tid + j * EST;
        ok[j] = false; sv[j] = 0; p[j] = 0;
        if (e < EE && ew[e] == 1) {
            ok[j] = true;
            sv[j] = src[e];
            p[j] = atomicAdd(&cursor[dst[e]], 1);
        }
    }
#pragma unroll
    for (int j = 0; j < 4; j++) if (ok[j]) csrc[p[j]] = sv[j];
}

// ---------------- MFMA GEMM (m97-style LDS-staged): C[M,N] = A[M,K] @ B[K,N] ----------------
// 128x128 block, 4 waves 2x2 (64x64 per wave), BK=32, async global->LDS staging.
// EPI: 0 = store raw bf16, 1 = relu(acc*S[col] + T[col])
template <int EPI>
__global__ __launch_bounds__(256) void gemm_tile(const u16* __restrict__ A, const u16* __restrict__ BT,
                                                 u16* __restrict__ Cm,
                                                 const float* __restrict__ S, const float* __restrict__ T,
                                                 int M, int N, int K) {
    __shared__ u16 As[128 * 32];   // [row][k] row-major, unpadded (global_load_lds layout)
    __shared__ u16 Bs[128 * 32];   // [col][k]
    const int tid  = threadIdx.x;
    const int wave = tid >> 6;
    const int lane = tid & 63;
    const int quad = lane >> 4;
    const int l16  = lane & 15;
    const int wr0  = (wave >> 1) * 64;
    const int wc0  = (wave & 1) * 64;
    const int row0 = blockIdx.x * 128;
    const int col0 = blockIdx.y * 128;

    const int lr = lane >> 2;          // 0..15 row within 16-row segment
    const int lk = (lane & 3) * 8;     // 0,8,16,24 element offset in k
    int r0l = wave * 32 + lr;
    int r1l = r0l + 16;
    int gr0 = row0 + r0l; if (gr0 >= M) gr0 = M - 1;   // clamp: loads valid, stores guarded
    int gr1 = row0 + r1l; if (gr1 >= M) gr1 = M - 1;
    const u16* ga0 = A  + (size_t)gr0 * K + lk;
    const u16* ga1 = A  + (size_t)gr1 * K + lk;
    const u16* gb0 = BT + (size_t)(col0 + r0l) * K + lk;
    const u16* gb1 = BT + (size_t)(col0 + r1l) * K + lk;
    u16* la0 = As + (size_t)(wave * 32)      * 32 + lane * 8;
    u16* la1 = As + (size_t)(wave * 32 + 16) * 32 + lane * 8;
    u16* lb0 = Bs + (size_t)(wave * 32)      * 32 + lane * 8;
    u16* lb1 = Bs + (size_t)(wave * 32 + 16) * 32 + lane * 8;

    f32x4_t acc[4][4];
#pragma unroll
    for (int r = 0; r < 4; r++)
#pragma unroll
        for (int c = 0; c < 4; c++)
#pragma unroll
            for (int i = 0; i < 4; i++) acc[r][c][i] = 0.f;

    for (int k0 = 0; k0 < K; k0 += 32) {
        gl_lds16(ga0 + k0, la0);
        gl_lds16(ga1 + k0, la1);
        gl_lds16(gb0 + k0, lb0);
        gl_lds16(gb1 + k0, lb1);
        __syncthreads();   // drains vmcnt (async LDS writes) + all waves

        bf16x8_t a[4], b[4];
#pragma unroll
        for (int r = 0; r < 4; r++)
            a[r] = *(const bf16x8_t*)(As + (size_t)(wr0 + r * 16 + l16) * 32 + quad * 8);
#pragma unroll
        for (int c = 0; c < 4; c++)
            b[c] = *(const bf16x8_t*)(Bs + (size_t)(wc0 + c * 16 + l16) * 32 + quad * 8);
#pragma unroll
        for (int r = 0; r < 4; r++)
#pragma unroll
            for (int c = 0; c < 4; c++)
                acc[r][c] = __builtin_amdgcn_mfma_f32_16x16x32_bf16(a[r], b[c], acc[r][c], 0, 0, 0);
        __syncthreads();   // LDS reads done before next staging overwrites
    }

#pragma unroll
    for (int r = 0; r < 4; r++) {
        int rb = row0 + wr0 + r * 16 + quad * 4;
#pragma unroll
        for (int c = 0; c < 4; c++) {
            int col = col0 + wc0 + c * 16 + l16;
            float sc = (EPI == 1) ? S[col] : 0.f;
            float sh = (EPI == 1) ? T[col] : 0.f;
#pragma unroll
            for (int i = 0; i < 4; i++) {
                int row = rb + i;
                if (row < M) {
                    float v = acc[r][c][i];
                    if (EPI == 1) v = fmaxf(v * sc + sh, 0.f);
                    Cm[(size_t)row * N + col] = f2bf(v);
                }
            }
        }
    }
}

// ---------------- GAT: per-node attention logits ----------------
__global__ __launch_bounds__(256) void gat_logits(const u16* __restrict__ xw, const u16* __restrict__ asrc,
                                                  const u16* __restrict__ adst, float* __restrict__ ls,
                                                  float* __restrict__ ld) {
    int n = blockIdx.x * 4 + (threadIdx.x >> 6);
    if (n >= NN) return;
    int lane = threadIdx.x & 63;
    uint4 xv = ((const uint4*)(xw + (size_t)n * C1))[lane];
    uint4 sv = ((const uint4*)asrc)[lane];
    uint4 dv = ((const uint4*)adst)[lane];
    float x[8], a[8], d[8];
    unpack8(xv, x); unpack8(sv, a); unpack8(dv, d);
    float ps = 0.f, pd = 0.f;
#pragma unroll
    for (int j = 0; j < 8; j++) { ps += x[j] * a[j]; pd += x[j] * d[j]; }
#pragma unroll
    for (int m = 16; m >= 1; m >>= 1) { ps += __shfl_xor(ps, m); pd += __shfl_xor(pd, m); }
    if ((lane & 31) == 0) {
        int h = lane >> 5;
        ls[n * 2 + h] = ps;
        ld[n * 2 + h] = pd;
    }
}

// ---------------- global max of ls per head (multi-block atomicMax, encoded) ----------------
__global__ __launch_bounds__(256) void ls_max(const float* __restrict__ ls, unsigned* __restrict__ gmx) {
    int tid = blockIdx.x * 256 + threadIdx.x;
    float m0 = -1e30f, m1 = -1e30f;
    for (int n = tid; n < NN; n += 40 * 256) {
        float2 v = ((const float2*)ls)[n];
        m0 = fmaxf(m0, v.x); m1 = fmaxf(m1, v.y);
    }
#pragma unroll
    for (int o = 32; o >= 1; o >>= 1) {
        m0 = fmaxf(m0, __shfl_xor(m0, o));
        m1 = fmaxf(m1, __shfl_xor(m1, o));
    }
    if ((threadIdx.x & 63) == 0) {
        atomicMax(&gmx[0], encf(m0));
        atomicMax(&gmx[1], encf(m1));
    }
}

// ---------------- fused GAT aggregation: single-sweep online softmax + gather ----------------
// one wave per node; lanes 0..31 head 0, 32..63 head 1; lane covers features [lane*8, lane*8+8)
// p = exp(v - mhat) with mhat = leaky(gmax + ld) an upper bound => p <= 1, no overflow;
// alpha = p / sum(p) is shift-invariant so result matches the reference exactly.
__global__ __launch_bounds__(256) void gat_aggregate(const int* __restrict__ off, const int* __restrict__ csrc,
                                                     const float* __restrict__ ls, const float* __restrict__ ld,
                                                     const unsigned* __restrict__ gmx, const u16* __restrict__ xw,
                                                     const float* __restrict__ bias, u16* __restrict__ outh) {
    int n = blockIdx.x * 4 + (threadIdx.x >> 6);
    if (n >= NN) return;
    int lane = threadIdx.x & 63;
    int h = lane >> 5;
    int beg = off[n], end = off[n + 1];
    float ldh = ld[n * 2 + h];
    float gm = decf(gmx[h]) + ldh;
    float mhat = gm > 0.f ? gm : 0.2f * gm;   // leaky is monotone -> valid upper bound

    float acc[8];
#pragma unroll
    for (int j = 0; j < 8; j++) acc[j] = 0.f;
    float den = 0.f;

    float lsv = 0.f; uint4 row;
    if (beg < end) {
        int s0 = csrc[beg];
        lsv = ls[s0 * 2 + h];
        row = ((const uint4*)(xw + (size_t)s0 * C1))[lane];
    }
    for (int i = beg; i < end; i++) {
        float cls = lsv;
        uint4 crow = row;
        if (i + 1 < end) {                       // prefetch next edge (1-deep pipeline)
            int s2 = csrc[i + 1];
            lsv = ls[s2 * 2 + h];
            row = ((const uint4*)(xw + (size_t)s2 * C1))[lane];
        }
        float v = cls + ldh;
        v = v > 0.f ? v : 0.2f * v;
        float p = __expf(v - mhat);
        den += p;
        float x[8];
        unpack8(crow, x);
#pragma unroll
        for (int j = 0; j < 8; j++) acc[j] = fmaf(p, x[j], acc[j]);
    }

    float inv = 1.f / fmaxf(den, 1e-30f);
    ushort4 r0, r1;
    int cb = lane * 8;
    float o0 = acc[0] * inv + bias[cb + 0], o1 = acc[1] * inv + bias[cb + 1];
    float o2 = acc[2] * inv + bias[cb + 2], o3 = acc[3] * inv + bias[cb + 3];
    float o4 = acc[4] * inv + bias[cb + 4], o5 = acc[5] * inv + bias[cb + 5];
    float o6 = acc[6] * inv + bias[cb + 6], o7 = acc[7] * inv + bias[cb + 7];
    r0.x = f2bf(o0); r0.y = f2bf(o1); r0.z = f2bf(o2); r0.w = f2bf(o3);
    r1.x = f2bf(o4); r1.y = f2bf(o5); r1.z = f2bf(o6); r1.w = f2bf(o7);
    ushort4* dst4 = (ushort4*)(outh + (size_t)n * C1 + cb);
    dst4[0] = r0; dst4[1] = r1;
}

// ---------------- fused pool + BN3 + ReLU (block per graph; batch is sorted) ----------------
__global__ __launch_bounds__(512) void pool_bn(const u16* __restrict__ h4, const int* __restrict__ goff,
                                               const float* __restrict__ S3, const float* __restrict__ T3,
                                               u16* __restrict__ z1) {
    int g = blockIdx.x, t = threadIdx.x;
    int b = goff[g], e = goff[g + 1];
    float s = 0.f;
    for (int n = b; n < e; n++) s += bf2f(h4[(size_t)n * C1 + t]);
    float mean = s / fmaxf((float)(e - b), 1.f);
    float v = mean * S3[t] + T3[t];
    z1[(size_t)g * C1 + t] = f2bf(fmaxf(v, 0.f));
}

// ---------------- head ----------------
__global__ __launch_bounds__(512) void head_fc1(const unsigned* __restrict__ flag, const u16* __restrict__ z1,
                                                const void* __restrict__ w1, const float* __restrict__ FB1,
                                                u16* __restrict__ z2) {
    __shared__ float zrow[512];
    int g = blockIdx.x, t = threadIdx.x;
    zrow[t] = bf2f(z1[(size_t)g * 512 + t]);
    __syncthreads();
    float acc = 0.f;
    if (*flag) {
        const float* w = (const float*)w1;
        for (int k = 0; k < 512; k++) acc = fmaf(zrow[k], w[(size_t)k * 512 + t], acc);
    } else {
        const u16* w = (const u16*)w1;
        for (int k = 0; k < 512; k++) acc = fmaf(zrow[k], bf2f(w[(size_t)k * 512 + t]), acc);
    }
    acc += FB1[t];
    z2[(size_t)g * 512 + t] = f2bf(fmaxf(acc, 0.f));
}
__global__ __launch_bounds__(64) void head_fc2(const unsigned* __restrict__ flag, const u16* __restrict__ z2,
                                               const void* __restrict__ w2, const float* __restrict__ FB2,
                                               void* __restrict__ out) {
    int g = blockIdx.x, o = blockIdx.y, lane = threadIdx.x;
    unsigned f = *flag;
    float acc = 0.f;
    if (f) {
        const float* w = (const float*)w2;
        for (int k = lane; k < 512; k += 64) acc += bf2f(z2[(size_t)g * 512 + k]) * w[(size_t)k * NC + o];
    } else {
        const u16* w = (const u16*)w2;
        for (int k = lane; k < 512; k += 64) acc += bf2f(z2[(size_t)g * 512 + k]) * bf2f(w[(size_t)k * NC + o]);
    }
#pragma unroll
    for (int m = 32; m >= 1; m >>= 1) acc += __shfl_xor(acc, m);
    if (lane == 0) {
        float v = acc + FB2[o];
        if (f) ((float*)out)[g * NC + o] = v;
        else   ((u16*)out)[g * NC + o] = f2bf(v);
    }
}

// ---------------- launch ----------------
extern "C" void kernel_launch(void* const* d_in, const int* in_sizes, int n_in,
                              void* d_out, int out_size, void* d_ws, size_t ws_size,
                              hipStream_t stream) {
    (void)in_sizes; (void)n_in; (void)out_size; (void)ws_size;

    const void* x      = d_in[0];
    const int* ei      = (const int*)d_in[1];
    const int* src     = ei;
    const int* dst     = ei + EE;
    const int* ew      = (const int*)d_in[2];
    const int* batch   = (const int*)d_in[3];
    const void* mlp_w1 = d_in[4];
    const void* mlp_b1 = d_in[5];
    const void *bn1g = d_in[6], *bn1b = d_in[7], *bn1m = d_in[8], *bn1v = d_in[9];
    const void* mlp_w2 = d_in[10];
    const void* mlp_b2 = d_in[11];
    const void *bn2g = d_in[12], *bn2b = d_in[13], *bn2m = d_in[14], *bn2v = d_in[15];
    const void* g0w    = d_in[16];
    const void* g0as   = d_in[17];
    const void* g0ad   = d_in[18];
    const void* g0bias = d_in[19];
    const void* g1w    = d_in[20];
    const void* g1as   = d_in[21];
    const void* g1ad   = d_in[22];
    const void* g1bias = d_in[23];
    const void *bn3g = d_in[24], *bn3b = d_in[25], *bn3m = d_in[26], *bn3v = d_in[27];
    const void* fin_w1 = d_in[28];
    const void* fin_b1 = d_in[29];
    const void* fin_w2 = d_in[30];
    const void* fin_b2 = d_in[31];

    char* ws = (char*)d_ws;
    u16*  XB   = (u16*)(ws + OFF_XB);
    u16*  h1   = (u16*)(ws + OFF_H1);
    u16*  h2   = (u16*)(ws + OFF_H2);
    u16*  xw   = (u16*)(ws + OFF_XW);
    u16*  h34  = (u16*)(ws + OFF_H34);
    float* ls  = (float*)(ws + OFF_LS);
    float* ld  = (float*)(ws + OFF_LD);
    int*  deg  = (int*)(ws + OFF_DEG);
    int*  off  = (int*)(ws + OFF_OFFS);
    int*  cur  = (int*)(ws + OFF_CUR);
    int*  csrc = (int*)(ws + OFF_CSRC);
    int*  gcnt = (int*)(ws + OFF_GCNT);
    int*  goff = (int*)(ws + OFF_GOFF);
    int*  part = (int*)(ws + OFF_PART);
    int*  ptot = (int*)(ws + OFF_PTOT);
    u16*  z1   = (u16*)(ws + OFF_Z1);
    u16*  z2   = (u16*)(ws + OFF_Z2);
    float* S1 = (float*)(ws + OFF_ST);
    float* T1 = S1 + 256;
    float* S2 = T1 + 256;
    float* T2 = S2 + 256;
    float* S3 = T2 + 256;
    float* T3 = S3 + 512;
    u16* w1T = (u16*)(ws + OFF_W1T);
    u16* w2T = (u16*)(ws + OFF_W2T);
    u16* g0T = (u16*)(ws + OFF_G0T);
    u16* g1T = (u16*)(ws + OFF_G1T);
    unsigned* flag = (unsigned*)(ws + OFF_FLAG);
    u16* A0S = (u16*)(ws + OFF_A0S);
    u16* A0D = (u16*)(ws + OFF_A0D);
    u16* A1S = (u16*)(ws + OFF_A1S);
    u16* A1D = (u16*)(ws + OFF_A1D);
    float* GB0 = (float*)(ws + OFF_GB0);
    float* GB1 = (float*)(ws + OFF_GB1);
    float* FB1 = (float*)(ws + OFF_FB1);
    float* FB2 = (float*)(ws + OFF_FB2);
    unsigned* GMXU = (unsigned*)(ws + OFF_GMX);   // [0..1]=layer0, [2..3]=layer1

    // dtype detection + input normalization (+ deg/gcnt/gmx init)
    detect_dtype<<<1, 256, 0, stream>>>((const u16*)x, (const u16*)mlp_w1, (const u16*)fin_w1, flag);
    cvt_x<<<(NN * FD / 4) / 256, 256, 0, stream>>>(flag, x, XB, deg, gcnt, GMXU);
    prep_params<<<1, 512, 0, stream>>>(flag,
                                       bn1g, bn1b, bn1m, bn1v, mlp_b1,
                                       bn2g, bn2b, bn2m, bn2v, mlp_b2,
                                       bn3g, bn3b, bn3m, bn3v,
                                       g0as, g0ad, g0bias, g1as, g1ad, g1bias,
                                       fin_b1, fin_b2,
                                       S1, T1, S2, T2, S3, T3,
                                       A0S, A0D, A1S, A1D, GB0, GB1, FB1, FB2);
    transpose_all<<<1920, 256, 0, stream>>>(flag, mlp_w1, mlp_w2, g0w, g1w, w1T, w2T, g0T, g1T);

    // CSR build (graph fixed across both layers) + graph offsets
    hist_k<<<HB, 256, 0, stream>>>(dst, ew, batch, deg, gcnt);
    scan_blk<<<NBLK, 256, 0, stream>>>(deg, off, part);
    scan_small<<<1, 128, 0, stream>>>(part, ptot, gcnt, goff);
    scan_add<<<NBLK, 256, 0, stream>>>(off, part, ptot, cur);
    csr_fill<<<HB, 256, 0, stream>>>(src, dst, ew, cur, csrc);

    // MLP (157 row-blocks of 128 cover 20096 >= 20000)
    gemm_tile<1><<<dim3(157, 2), 256, 0, stream>>>(XB, w1T, h1, S1, T1, NN, C0, FD);
    gemm_tile<1><<<dim3(157, 2), 256, 0, stream>>>(h1, w2T, h2, S2, T2, NN, C0, C0);

    // GAT layer 0
    gemm_tile<0><<<dim3(157, 4), 256, 0, stream>>>(h2, g0T, xw, nullptr, nullptr, NN, C1, C0);
    gat_logits<<<NN / 4, 256, 0, stream>>>(xw, A0S, A0D, ls, ld);
    ls_max<<<40, 256, 0, stream>>>(ls, GMXU);
    gat_aggregate<<<NN / 4, 256, 0, stream>>>(off, csrc, ls, ld, GMXU, xw, GB0, h34);

    // GAT layer 1
    gemm_tile<0><<<dim3(157, 4), 256, 0, stream>>>(h34, g1T, xw, nullptr, nullptr, NN, C1, C1);
    gat_logits<<<NN / 4, 256, 0, stream>>>(xw, A1S, A1D, ls, ld);
    ls_max<<<40, 256, 0, stream>>>(ls, GMXU + 2);
    gat_aggregate<<<NN / 4, 256, 0, stream>>>(off, csrc, ls, ld, GMXU + 2, xw, GB1, h34);  // h4

    // pool + head
    pool_bn<<<NG, 512, 0, stream>>>(h34, goff, S3, T3, z1);
    head_fc1<<<NG, 512, 0, stream>>>(flag, z1, fin_w1, FB1, z2);
    head_fc2<<<dim3(NG, NC), 64, 0, stream>>>(flag, z2, fin_w2, FB2, d_out);
}